// Round 1
// baseline (693.317 us; speedup 1.0000x reference)
//
#include <hip/hip_runtime.h>
#include <hip/hip_bf16.h>
#include <math.h>

#define NEG 0.01f
#define MAXDEG_LDS 512

// ---------------- wave helpers (wave = 64) ----------------
__device__ __forceinline__ float wred_max(float v){
#pragma unroll
  for (int o=32;o>0;o>>=1) v = fmaxf(v, __shfl_down(v,o,64));
  return v;
}
__device__ __forceinline__ float wred_sum(float v){
#pragma unroll
  for (int o=32;o>0;o>>=1) v += __shfl_down(v,o,64);
  return v;
}
__device__ __forceinline__ int wred_sum_i(int v){
#pragma unroll
  for (int o=32;o>0;o>>=1) v += __shfl_down(v,o,64);
  return v;
}

// ---------------- CSR build ----------------
__global__ void zero_i32(int* p, int n){
  int i = blockIdx.x*blockDim.x + threadIdx.x;
  if (i<n) p[i]=0;
}

__global__ void hist_k(const int* __restrict__ dst, int* __restrict__ cnt, int E){
  int i = blockIdx.x*blockDim.x+threadIdx.x;
  if (i<E) atomicAdd(&cnt[dst[i]], 1);
}

// chunk = 1024 elements per block (256 thr x 4)
__global__ void scan_partial_k(const int* __restrict__ cnt, int* __restrict__ bsum, int n){
  int b = blockIdx.x, t = threadIdx.x;
  int base = b*1024 + t*4;
  int s=0;
#pragma unroll
  for (int i=0;i<4;i++){ int idx=base+i; if(idx<n) s+=cnt[idx]; }
  int ws = wred_sum_i(s);
  __shared__ int sw[4];
  int wave=t>>6, lane=t&63;
  if (lane==0) sw[wave]=ws;
  __syncthreads();
  if (t==0) bsum[b] = sw[0]+sw[1]+sw[2]+sw[3];
}

__global__ void scan_bsums_k(const int* __restrict__ bsum, int* __restrict__ bpre,
                             int nb, int* __restrict__ row_off, int n, int E){
  if (threadIdx.x==0 && blockIdx.x==0){
    int c=0;
    for (int i=0;i<nb;i++){ bpre[i]=c; c+=bsum[i]; }
    row_off[n]=E;
  }
}

__global__ void scan_final_k(const int* __restrict__ cnt, const int* __restrict__ bpre,
                             int* __restrict__ row_off, int* __restrict__ cursor, int n){
  int b=blockIdx.x, t=threadIdx.x;
  int lane=t&63, wave=t>>6;
  int base=b*1024 + t*4;
  int v[4]; int ts=0;
#pragma unroll
  for (int i=0;i<4;i++){ int idx=base+i; v[i]=(idx<n)?cnt[idx]:0; ts+=v[i]; }
  int x=ts;
#pragma unroll
  for (int o=1;o<64;o<<=1){ int y=__shfl_up(x,o,64); if (lane>=o) x+=y; }
  __shared__ int sw[4];
  if (lane==63) sw[wave]=x;
  __syncthreads();
  int wpre=0;
  for (int w=0;w<wave;w++) wpre+=sw[w];
  int run = bpre[b] + wpre + (x - ts);
#pragma unroll
  for (int i=0;i<4;i++){ int idx=base+i; if(idx<n){ row_off[idx]=run; cursor[idx]=run; } run+=v[i]; }
}

__global__ void scatter_k(const int* __restrict__ src, const int* __restrict__ dst,
                          int* __restrict__ cursor, int* __restrict__ col, int E){
  int i=blockIdx.x*blockDim.x+threadIdx.x;
  if (i<E){ int slot=atomicAdd(&cursor[dst[i]],1); col[slot]=src[i]; }
}

// ---------------- GEMM: C(n x 256) = A(n x 256) @ W(256 x 256)^T ----------------
__global__ __launch_bounds__(256) void gemm_k(const float* __restrict__ A,
      const float* __restrict__ W, float* __restrict__ C, int n){
  __shared__ float As[32][68];
  __shared__ float Bs[32][68];
  int bm = blockIdx.x*64, bn = blockIdx.y*64;
  int tid=threadIdx.x;
  int tx=tid&15, ty=tid>>4;
  int lk = tid&31, lr = tid>>5;
  float acc[4][4]={};
  for (int bk=0;bk<256;bk+=32){
#pragma unroll
    for (int rr=0;rr<8;rr++){
      int r = lr + rr*8;
      int gr = bm + r;
      As[lk][r] = (gr<n) ? A[gr*256 + bk + lk] : 0.0f;
      Bs[lk][r] = W[(bn+r)*256 + bk + lk];
    }
    __syncthreads();
#pragma unroll
    for (int k=0;k<32;k++){
      float a[4],b[4];
#pragma unroll
      for (int i=0;i<4;i++) a[i]=As[k][ty*4+i];
#pragma unroll
      for (int j=0;j<4;j++) b[j]=Bs[k][tx*4+j];
#pragma unroll
      for (int i=0;i<4;i++)
#pragma unroll
        for (int j=0;j<4;j++) acc[i][j] += a[i]*b[j];
    }
    __syncthreads();
  }
#pragma unroll
  for (int i=0;i<4;i++){
    int gr=bm+ty*4+i;
    if (gr<n){
#pragma unroll
      for (int j=0;j<4;j++) C[gr*256 + bn + tx*4 + j] = acc[i][j];
    }
  }
}

// ---------------- attention-score dot products ----------------
// layer 1: es[n,h] = dot(z[n,h,:], a1[h,0:64]); ed[n,h] = dot(z[n,h,:], a1[h,64:128])
__global__ void dots1_k(const float* __restrict__ z, const float* __restrict__ a1,
                        float* __restrict__ es, float* __restrict__ ed, int n){
  int wave=threadIdx.x>>6, lane=threadIdx.x&63;
  int nd = blockIdx.x*4 + wave;
  if (nd>=n) return;
#pragma unroll
  for (int hh=0;hh<4;hh++){
    float zv = z[nd*256 + hh*64 + lane];
    float s = wred_sum(zv * a1[hh*128 + lane]);
    float d = wred_sum(zv * a1[hh*128 + 64 + lane]);
    if (lane==0){ es[nd*4+hh]=s; ed[nd*4+hh]=d; }
  }
}

// layer 2: e2s[n] = dot(z2[n,:], a2[0:256]); e2d[n] = dot(z2[n,:], a2[256:512])
__global__ void dots2_k(const float* __restrict__ z2, const float* __restrict__ a2,
                        float* __restrict__ e2s, float* __restrict__ e2d, int n){
  int wave=threadIdx.x>>6, lane=threadIdx.x&63;
  int nd=blockIdx.x*4+wave;
  if (nd>=n) return;
  float s=0.f,d=0.f;
#pragma unroll
  for (int c=0;c<4;c++){
    float zv=z2[nd*256 + c*64 + lane];
    s += zv*a2[c*64+lane];
    d += zv*a2[256 + c*64+lane];
  }
  s=wred_sum(s); d=wred_sum(d);
  if (lane==0){ e2s[nd]=s; e2d[nd]=d; }
}

// ---------------- layer-1 softmax + aggregate (4 heads), writes h1 = elu(m) ----------------
__global__ __launch_bounds__(256) void agg1_k(const float* __restrict__ z,
    const float* __restrict__ es, const float* __restrict__ ed,
    const int* __restrict__ row_off, const int* __restrict__ col,
    float* __restrict__ h1){
  int nd = blockIdx.x;
  int tid=threadIdx.x, lane=tid&63, wave=tid>>6;
  int beg=row_off[nd], deg=row_off[nd+1]-beg;
  __shared__ int s_src[MAXDEG_LDS];
  __shared__ float s_ev[MAXDEG_LDS][4];
  __shared__ float s_red[4][4];
  float edv[4];
#pragma unroll
  for (int hh=0;hh<4;hh++) edv[hh]=ed[nd*4+hh];
  float lmax[4]={-1e30f,-1e30f,-1e30f,-1e30f};
  for (int j=tid;j<deg;j+=256){
    int s=col[beg+j];
    if (j<MAXDEG_LDS) s_src[j]=s;
#pragma unroll
    for (int hh=0;hh<4;hh++){
      float ev = es[s*4+hh]+edv[hh];
      ev = ev>0.f? ev : NEG*ev;
      if (j<MAXDEG_LDS) s_ev[j][hh]=ev;
      lmax[hh]=fmaxf(lmax[hh],ev);
    }
  }
#pragma unroll
  for (int hh=0;hh<4;hh++){
    float m=wred_max(lmax[hh]);
    if (lane==0) s_red[wave][hh]=m;
  }
  __syncthreads();
  float gmax[4];
#pragma unroll
  for (int hh=0;hh<4;hh++)
    gmax[hh]=fmaxf(fmaxf(s_red[0][hh],s_red[1][hh]),fmaxf(s_red[2][hh],s_red[3][hh]));
  __syncthreads();
  float lsum[4]={0.f,0.f,0.f,0.f};
  for (int j=tid;j<deg;j+=256){
#pragma unroll
    for (int hh=0;hh<4;hh++){
      float ev;
      if (j<MAXDEG_LDS) ev=s_ev[j][hh];
      else { int s=col[beg+j]; ev=es[s*4+hh]+edv[hh]; ev=ev>0.f?ev:NEG*ev; }
      float ex=__expf(ev-gmax[hh]);
      if (j<MAXDEG_LDS) s_ev[j][hh]=ex;
      lsum[hh]+=ex;
    }
  }
#pragma unroll
  for (int hh=0;hh<4;hh++){
    float s=wred_sum(lsum[hh]);
    if (lane==0) s_red[wave][hh]=s;
  }
  __syncthreads();
  float inv[4];
#pragma unroll
  for (int hh=0;hh<4;hh++) inv[hh]=1.0f/(s_red[0][hh]+s_red[1][hh]+s_red[2][hh]+s_red[3][hh]);
  int d=tid, hh=d>>6;
  float acc=0.f;
  for (int j=0;j<deg;j++){
    int s; float a;
    if (j<MAXDEG_LDS){ s=s_src[j]; a=s_ev[j][hh]; }
    else { s=col[beg+j]; float ev=es[s*4+hh]+edv[hh]; ev=ev>0.f?ev:NEG*ev; a=__expf(ev-gmax[hh]); }
    acc += a * z[s*256 + d];
  }
  float mv = acc*inv[hh];
  h1[nd*256+d] = mv>0.f? mv : __expf(mv)-1.0f;   // elu fused
}

// ---------------- layer-2 softmax + aggregate (1 head), writes out ----------------
__global__ __launch_bounds__(256) void agg2_k(const float* __restrict__ z2,
    const float* __restrict__ e2s, const float* __restrict__ e2d,
    const int* __restrict__ row_off, const int* __restrict__ col,
    float* __restrict__ out){
  int nd=blockIdx.x;
  int tid=threadIdx.x, lane=tid&63, wave=tid>>6;
  int beg=row_off[nd], deg=row_off[nd+1]-beg;
  __shared__ int s_src[MAXDEG_LDS];
  __shared__ float s_ev[MAXDEG_LDS];
  __shared__ float s_red[4];
  float edv=e2d[nd];
  float lmax=-1e30f;
  for (int j=tid;j<deg;j+=256){
    int s=col[beg+j];
    if (j<MAXDEG_LDS) s_src[j]=s;
    float ev=e2s[s]+edv; ev=ev>0.f?ev:NEG*ev;
    if (j<MAXDEG_LDS) s_ev[j]=ev;
    lmax=fmaxf(lmax,ev);
  }
  float m=wred_max(lmax);
  if (lane==0) s_red[wave]=m;
  __syncthreads();
  float gmax=fmaxf(fmaxf(s_red[0],s_red[1]),fmaxf(s_red[2],s_red[3]));
  __syncthreads();
  float lsum=0.f;
  for (int j=tid;j<deg;j+=256){
    float ev;
    if (j<MAXDEG_LDS) ev=s_ev[j];
    else { int s=col[beg+j]; ev=e2s[s]+edv; ev=ev>0.f?ev:NEG*ev; }
    float ex=__expf(ev-gmax);
    if (j<MAXDEG_LDS) s_ev[j]=ex;
    lsum+=ex;
  }
  float ssum=wred_sum(lsum);
  if (lane==0) s_red[wave]=ssum;
  __syncthreads();
  float inv=1.0f/(s_red[0]+s_red[1]+s_red[2]+s_red[3]);
  int d=tid;
  float acc=0.f;
  for (int j=0;j<deg;j++){
    int s2; float a;
    if (j<MAXDEG_LDS){ s2=s_src[j]; a=s_ev[j]; }
    else { s2=col[beg+j]; float ev=e2s[s2]+edv; ev=ev>0.f?ev:NEG*ev; a=__expf(ev-gmax); }
    acc += a*z2[s2*256+d];
  }
  out[nd*256+d]=acc*inv;
}

// ---------------- launch ----------------
extern "C" void kernel_launch(void* const* d_in, const int* in_sizes, int n_in,
                              void* d_out, int out_size, void* d_ws, size_t ws_size,
                              hipStream_t stream){
  const float* h  = (const float*)d_in[0];
  const float* W1 = (const float*)d_in[1];
  const float* a1 = (const float*)d_in[2];
  const float* W2 = (const float*)d_in[3];
  const float* a2 = (const float*)d_in[4];
  const int* src  = (const int*)d_in[5];
  const int* dst  = (const int*)d_in[6];
  float* out = (float*)d_out;
  int N = in_sizes[0]/256;   // 50000
  int E = in_sizes[5];       // 850000

  char* p=(char*)d_ws;
  auto alloc=[&](size_t bytes)->void*{ void* r=(void*)p; p += (bytes+255)&~(size_t)255; return r; };
  float* z   =(float*)alloc(sizeof(float)*(size_t)N*256);
  float* h1  =(float*)alloc(sizeof(float)*(size_t)N*256);
  float* z2  =(float*)alloc(sizeof(float)*(size_t)N*256);
  float* es  =(float*)alloc(sizeof(float)*(size_t)N*4);
  float* ed  =(float*)alloc(sizeof(float)*(size_t)N*4);
  float* e2s =(float*)alloc(sizeof(float)*(size_t)N);
  float* e2d =(float*)alloc(sizeof(float)*(size_t)N);
  int* cnt    =(int*)alloc(sizeof(int)*(size_t)N);
  int* row_off=(int*)alloc(sizeof(int)*(size_t)(N+1));
  int* cursor =(int*)alloc(sizeof(int)*(size_t)N);
  int* col    =(int*)alloc(sizeof(int)*(size_t)E);
  int* bsum   =(int*)alloc(sizeof(int)*64);
  int* bpre   =(int*)alloc(sizeof(int)*64);

  int nb = (N+1023)/1024;

  zero_i32<<<(N+255)/256,256,0,stream>>>(cnt,N);
  hist_k<<<(E+255)/256,256,0,stream>>>(dst,cnt,E);
  scan_partial_k<<<nb,256,0,stream>>>(cnt,bsum,N);
  scan_bsums_k<<<1,64,0,stream>>>(bsum,bpre,nb,row_off,N,E);
  scan_final_k<<<nb,256,0,stream>>>(cnt,bpre,row_off,cursor,N);
  scatter_k<<<(E+255)/256,256,0,stream>>>(src,dst,cursor,col,E);

  dim3 gg((N+63)/64, 4);
  gemm_k<<<gg,256,0,stream>>>(h,W1,z,N);
  dots1_k<<<(N+3)/4,256,0,stream>>>(z,a1,es,ed,N);
  agg1_k<<<N,256,0,stream>>>(z,es,ed,row_off,col,h1);
  gemm_k<<<gg,256,0,stream>>>(h1,W2,z2,N);
  dots2_k<<<(N+3)/4,256,0,stream>>>(z2,a2,e2s,e2d,N);
  agg2_k<<<N,256,0,stream>>>(z2,e2s,e2d,row_off,col,out);
}

// Round 2
// 683.328 us; speedup vs baseline: 1.0146x; 1.0146x over previous
//
#include <hip/hip_runtime.h>
#include <hip/hip_bf16.h>
#include <math.h>

#define NEG 0.01f
#define MAXDEG_LDS 512

// ---------------- helpers ----------------
__device__ __forceinline__ float wred_max(float v){
#pragma unroll
  for (int o=32;o>0;o>>=1) v = fmaxf(v, __shfl_down(v,o,64));
  return v;
}
__device__ __forceinline__ float wred_sum(float v){
#pragma unroll
  for (int o=32;o>0;o>>=1) v += __shfl_down(v,o,64);
  return v;
}
__device__ __forceinline__ int wred_sum_i(int v){
#pragma unroll
  for (int o=32;o>0;o>>=1) v += __shfl_down(v,o,64);
  return v;
}
__device__ __forceinline__ float bf2f(unsigned u){   // u: bf16 bits in low 16
  union{unsigned i; float f;} c; c.i = u<<16; return c.f;
}
__device__ __forceinline__ unsigned short f2bf(float f){  // round-to-nearest-even
  union{float f; unsigned i;} c; c.f=f;
  unsigned r = c.i + 0x7fffu + ((c.i>>16)&1u);
  return (unsigned short)(r>>16);
}

// ---------------- CSR build ----------------
__global__ void zero_k(int* __restrict__ cnt, float* __restrict__ e2s,
                       float* __restrict__ e2d, int n){
  int i = blockIdx.x*blockDim.x + threadIdx.x;
  if (i<n){ cnt[i]=0; e2s[i]=0.f; e2d[i]=0.f; }
}

__global__ void hist_k(const int* __restrict__ dst, int* __restrict__ cnt, int E){
  int i = blockIdx.x*blockDim.x+threadIdx.x;
  if (i<E) atomicAdd(&cnt[dst[i]], 1);
}

__global__ void scan_partial_k(const int* __restrict__ cnt, int* __restrict__ bsum, int n){
  int b = blockIdx.x, t = threadIdx.x;
  int base = b*1024 + t*4;
  int s=0;
#pragma unroll
  for (int i=0;i<4;i++){ int idx=base+i; if(idx<n) s+=cnt[idx]; }
  int ws = wred_sum_i(s);
  __shared__ int sw[4];
  int wave=t>>6, lane=t&63;
  if (lane==0) sw[wave]=ws;
  __syncthreads();
  if (t==0) bsum[b] = sw[0]+sw[1]+sw[2]+sw[3];
}

__global__ void scan_bsums_k(const int* __restrict__ bsum, int* __restrict__ bpre,
                             int nb, int* __restrict__ row_off, int n, int E){
  if (threadIdx.x==0 && blockIdx.x==0){
    int c=0;
    for (int i=0;i<nb;i++){ bpre[i]=c; c+=bsum[i]; }
    row_off[n]=E;
  }
}

__global__ void scan_final_k(const int* __restrict__ cnt, const int* __restrict__ bpre,
                             int* __restrict__ row_off, int* __restrict__ cursor, int n){
  int b=blockIdx.x, t=threadIdx.x;
  int lane=t&63, wave=t>>6;
  int base=b*1024 + t*4;
  int v[4]; int ts=0;
#pragma unroll
  for (int i=0;i<4;i++){ int idx=base+i; v[i]=(idx<n)?cnt[idx]:0; ts+=v[i]; }
  int x=ts;
#pragma unroll
  for (int o=1;o<64;o<<=1){ int y=__shfl_up(x,o,64); if (lane>=o) x+=y; }
  __shared__ int sw[4];
  if (lane==63) sw[wave]=x;
  __syncthreads();
  int wpre=0;
  for (int w=0;w<wave;w++) wpre+=sw[w];
  int run = bpre[b] + wpre + (x - ts);
#pragma unroll
  for (int i=0;i<4;i++){ int idx=base+i; if(idx<n){ row_off[idx]=run; cursor[idx]=run; } run+=v[i]; }
}

__global__ void scatter_k(const int* __restrict__ src, const int* __restrict__ dst,
                          int* __restrict__ cursor, int* __restrict__ col, int E){
  int i=blockIdx.x*blockDim.x+threadIdx.x;
  if (i<E){ int slot=atomicAdd(&cursor[dst[i]],1); col[slot]=src[i]; }
}

// ---------------- GEMM1: z(n x 256) = A @ W1^T, bf16 out + fused es/ed (f32) ----------------
// blockIdx.y = head (64-dim quadrant)
__global__ __launch_bounds__(256) void gemm1_k(const float* __restrict__ A,
      const float* __restrict__ W, const float* __restrict__ a1,
      unsigned short* __restrict__ zb, float* __restrict__ es, float* __restrict__ ed, int n){
  __shared__ float As[32][68];
  __shared__ float Bs[32][68];
  __shared__ float s_es[64][17];
  __shared__ float s_ed[64][17];
  int bm = blockIdx.x*64, bn = blockIdx.y;   // bn = head
  int tid=threadIdx.x, tx=tid&15, ty=tid>>4;
  int lk=tid&31, lr=tid>>5;
  float acc[4][4]={};
  for (int bk=0;bk<256;bk+=32){
#pragma unroll
    for (int rr=0;rr<8;rr++){
      int r=lr+rr*8, gr=bm+r;
      As[lk][r] = (gr<n)? A[(size_t)gr*256+bk+lk] : 0.f;
      Bs[lk][r] = W[(size_t)(bn*64+r)*256 + bk + lk];
    }
    __syncthreads();
#pragma unroll
    for (int k=0;k<32;k++){
      float a[4],b[4];
#pragma unroll
      for (int i=0;i<4;i++) a[i]=As[k][ty*4+i];
#pragma unroll
      for (int j=0;j<4;j++) b[j]=Bs[k][tx*4+j];
#pragma unroll
      for (int i=0;i<4;i++)
#pragma unroll
        for (int j=0;j<4;j++) acc[i][j] += a[i]*b[j];
    }
    __syncthreads();
  }
  // bf16 z write (8B per thread-row)
#pragma unroll
  for (int i=0;i<4;i++){
    int gr=bm+ty*4+i;
    if (gr<n){
      union{ unsigned short u[4]; uint2 v; } pk;
#pragma unroll
      for (int j=0;j<4;j++) pk.u[j]=f2bf(acc[i][j]);
      *(uint2*)(zb + (size_t)gr*256 + bn*64 + tx*4) = pk.v;
    }
  }
  // fused es/ed in f32: this block covers all 64 dims of head bn
  float ws_[4], wd_[4];
#pragma unroll
  for (int j=0;j<4;j++){ ws_[j]=a1[bn*128 + tx*4+j]; wd_[j]=a1[bn*128 + 64 + tx*4+j]; }
#pragma unroll
  for (int i=0;i<4;i++){
    float pe=0.f, pd=0.f;
#pragma unroll
    for (int j=0;j<4;j++){ pe+=acc[i][j]*ws_[j]; pd+=acc[i][j]*wd_[j]; }
    s_es[ty*4+i][tx]=pe; s_ed[ty*4+i][tx]=pd;
  }
  __syncthreads();
  if (tid<64){
    float se=0.f, sd=0.f;
#pragma unroll
    for (int k=0;k<16;k++){ se+=s_es[tid][k]; sd+=s_ed[tid][k]; }
    int gr=bm+tid;
    if (gr<n){ es[gr*4+bn]=se; ed[gr*4+bn]=sd; }
  }
}

// ---------------- GEMM2: z2 = h1 @ W2^T, bf16 out + fused e2s/e2d partials (atomic f32) -------
__global__ __launch_bounds__(256) void gemm2_k(const float* __restrict__ A,
      const float* __restrict__ W, const float* __restrict__ a2,
      unsigned short* __restrict__ zb, float* __restrict__ e2s, float* __restrict__ e2d, int n){
  __shared__ float As[32][68];
  __shared__ float Bs[32][68];
  __shared__ float s_es[64][17];
  __shared__ float s_ed[64][17];
  int bm = blockIdx.x*64, bn = blockIdx.y;
  int tid=threadIdx.x, tx=tid&15, ty=tid>>4;
  int lk=tid&31, lr=tid>>5;
  float acc[4][4]={};
  for (int bk=0;bk<256;bk+=32){
#pragma unroll
    for (int rr=0;rr<8;rr++){
      int r=lr+rr*8, gr=bm+r;
      As[lk][r] = (gr<n)? A[(size_t)gr*256+bk+lk] : 0.f;
      Bs[lk][r] = W[(size_t)(bn*64+r)*256 + bk + lk];
    }
    __syncthreads();
#pragma unroll
    for (int k=0;k<32;k++){
      float a[4],b[4];
#pragma unroll
      for (int i=0;i<4;i++) a[i]=As[k][ty*4+i];
#pragma unroll
      for (int j=0;j<4;j++) b[j]=Bs[k][tx*4+j];
#pragma unroll
      for (int i=0;i<4;i++)
#pragma unroll
        for (int j=0;j<4;j++) acc[i][j] += a[i]*b[j];
    }
    __syncthreads();
  }
#pragma unroll
  for (int i=0;i<4;i++){
    int gr=bm+ty*4+i;
    if (gr<n){
      union{ unsigned short u[4]; uint2 v; } pk;
#pragma unroll
      for (int j=0;j<4;j++) pk.u[j]=f2bf(acc[i][j]);
      *(uint2*)(zb + (size_t)gr*256 + bn*64 + tx*4) = pk.v;
    }
  }
  float ws_[4], wd_[4];
#pragma unroll
  for (int j=0;j<4;j++){ ws_[j]=a2[bn*64 + tx*4+j]; wd_[j]=a2[256 + bn*64 + tx*4+j]; }
#pragma unroll
  for (int i=0;i<4;i++){
    float pe=0.f, pd=0.f;
#pragma unroll
    for (int j=0;j<4;j++){ pe+=acc[i][j]*ws_[j]; pd+=acc[i][j]*wd_[j]; }
    s_es[ty*4+i][tx]=pe; s_ed[ty*4+i][tx]=pd;
  }
  __syncthreads();
  if (tid<64){
    float se=0.f, sd=0.f;
#pragma unroll
    for (int k=0;k<16;k++){ se+=s_es[tid][k]; sd+=s_ed[tid][k]; }
    int gr=bm+tid;
    if (gr<n){ atomicAdd(&e2s[gr], se); atomicAdd(&e2d[gr], sd); }
  }
}

// ---------------- layer-1 softmax + aggregate (4 heads), h1 = elu(m) ----------------
__global__ __launch_bounds__(256) void agg1_k(const unsigned short* __restrict__ zb,
    const float* __restrict__ es, const float* __restrict__ ed,
    const int* __restrict__ row_off, const int* __restrict__ col,
    float* __restrict__ h1){
  int nd = blockIdx.x;
  int tid=threadIdx.x, lane=tid&63, wave=tid>>6;
  int beg=row_off[nd], deg=row_off[nd+1]-beg;
  __shared__ int s_src[MAXDEG_LDS];
  __shared__ float4 s_ev[MAXDEG_LDS];
  __shared__ float s_red[4][4];
  __shared__ float s_c[128][2];
  float4 edv = *(const float4*)(ed + (size_t)nd*4);
  float lmax[4]={-1e30f,-1e30f,-1e30f,-1e30f};
  for (int j=tid;j<deg;j+=256){
    int s=col[beg+j];
    float4 ev = *(const float4*)(es + (size_t)s*4);
    ev.x+=edv.x; ev.y+=edv.y; ev.z+=edv.z; ev.w+=edv.w;
    ev.x = ev.x>0.f?ev.x:NEG*ev.x;
    ev.y = ev.y>0.f?ev.y:NEG*ev.y;
    ev.z = ev.z>0.f?ev.z:NEG*ev.z;
    ev.w = ev.w>0.f?ev.w:NEG*ev.w;
    if (j<MAXDEG_LDS){ s_src[j]=s; s_ev[j]=ev; }
    lmax[0]=fmaxf(lmax[0],ev.x); lmax[1]=fmaxf(lmax[1],ev.y);
    lmax[2]=fmaxf(lmax[2],ev.z); lmax[3]=fmaxf(lmax[3],ev.w);
  }
#pragma unroll
  for (int hh=0;hh<4;hh++){
    float m=wred_max(lmax[hh]);
    if (lane==0) s_red[wave][hh]=m;
  }
  __syncthreads();
  float gmax[4];
#pragma unroll
  for (int hh=0;hh<4;hh++)
    gmax[hh]=fmaxf(fmaxf(s_red[0][hh],s_red[1][hh]),fmaxf(s_red[2][hh],s_red[3][hh]));
  __syncthreads();
  float lsum[4]={0.f,0.f,0.f,0.f};
  for (int j=tid;j<deg;j+=256){
    float4 ev;
    if (j<MAXDEG_LDS) ev=s_ev[j];
    else {
      int s=col[beg+j];
      ev = *(const float4*)(es + (size_t)s*4);
      ev.x+=edv.x; ev.y+=edv.y; ev.z+=edv.z; ev.w+=edv.w;
      ev.x = ev.x>0.f?ev.x:NEG*ev.x; ev.y = ev.y>0.f?ev.y:NEG*ev.y;
      ev.z = ev.z>0.f?ev.z:NEG*ev.z; ev.w = ev.w>0.f?ev.w:NEG*ev.w;
    }
    ev.x=__expf(ev.x-gmax[0]); ev.y=__expf(ev.y-gmax[1]);
    ev.z=__expf(ev.z-gmax[2]); ev.w=__expf(ev.w-gmax[3]);
    if (j<MAXDEG_LDS) s_ev[j]=ev;
    lsum[0]+=ev.x; lsum[1]+=ev.y; lsum[2]+=ev.z; lsum[3]+=ev.w;
  }
#pragma unroll
  for (int hh=0;hh<4;hh++){
    float s=wred_sum(lsum[hh]);
    if (lane==0) s_red[wave][hh]=s;
  }
  __syncthreads();
  float inv[4];
#pragma unroll
  for (int hh=0;hh<4;hh++) inv[hh]=1.0f/(s_red[0][hh]+s_red[1][hh]+s_red[2][hh]+s_red[3][hh]);
  // phase 3: 2 dims/thread, 2 edges in flight (parity split)
  int t = tid & 127, half = tid >> 7;
  int hh = t>>5;
  float acc0=0.f, acc1=0.f;
  for (int j=half;j<deg;j+=2){
    int s; float al;
    if (j<MAXDEG_LDS){ s=s_src[j]; al=((const float*)&s_ev[j])[hh]; }
    else {
      s=col[beg+j];
      float e = es[(size_t)s*4+hh] + ((const float*)&edv)[hh];
      e = e>0.f?e:NEG*e;
      al = __expf(e-gmax[hh]);
    }
    unsigned v = *(const unsigned*)(zb + (size_t)s*256 + 2*t);
    acc0 += al*bf2f(v & 0xffffu);
    acc1 += al*bf2f(v >> 16);
  }
  __syncthreads();
  if (half==1){ s_c[t][0]=acc0; s_c[t][1]=acc1; }
  __syncthreads();
  if (half==0){
    acc0 += s_c[t][0]; acc1 += s_c[t][1];
    float m0=acc0*inv[hh], m1=acc1*inv[hh];
    m0 = m0>0.f? m0 : __expf(m0)-1.0f;
    m1 = m1>0.f? m1 : __expf(m1)-1.0f;
    *(float2*)(h1 + (size_t)nd*256 + 2*t) = make_float2(m0,m1);
  }
}

// ---------------- layer-2 softmax + aggregate (1 head), writes out ----------------
__global__ __launch_bounds__(256) void agg2_k(const unsigned short* __restrict__ zb,
    const float* __restrict__ e2s, const float* __restrict__ e2d,
    const int* __restrict__ row_off, const int* __restrict__ col,
    float* __restrict__ out){
  int nd=blockIdx.x;
  int tid=threadIdx.x, lane=tid&63, wave=tid>>6;
  int beg=row_off[nd], deg=row_off[nd+1]-beg;
  __shared__ int s_src[MAXDEG_LDS];
  __shared__ float s_ev[MAXDEG_LDS];
  __shared__ float s_red[4];
  __shared__ float s_c[128][2];
  float edv=e2d[nd];
  float lmax=-1e30f;
  for (int j=tid;j<deg;j+=256){
    int s=col[beg+j];
    float ev=e2s[s]+edv; ev=ev>0.f?ev:NEG*ev;
    if (j<MAXDEG_LDS){ s_src[j]=s; s_ev[j]=ev; }
    lmax=fmaxf(lmax,ev);
  }
  float m=wred_max(lmax);
  if (lane==0) s_red[wave]=m;
  __syncthreads();
  float gmax=fmaxf(fmaxf(s_red[0],s_red[1]),fmaxf(s_red[2],s_red[3]));
  __syncthreads();
  float lsum=0.f;
  for (int j=tid;j<deg;j+=256){
    float ev;
    if (j<MAXDEG_LDS) ev=s_ev[j];
    else { int s=col[beg+j]; ev=e2s[s]+edv; ev=ev>0.f?ev:NEG*ev; }
    float ex=__expf(ev-gmax);
    if (j<MAXDEG_LDS) s_ev[j]=ex;
    lsum+=ex;
  }
  float ssum=wred_sum(lsum);
  if (lane==0) s_red[wave]=ssum;
  __syncthreads();
  float inv=1.0f/(s_red[0]+s_red[1]+s_red[2]+s_red[3]);
  int t = tid & 127, half = tid >> 7;
  float acc0=0.f, acc1=0.f;
  for (int j=half;j<deg;j+=2){
    int s; float al;
    if (j<MAXDEG_LDS){ s=s_src[j]; al=s_ev[j]; }
    else {
      s=col[beg+j];
      float e=e2s[s]+edv; e=e>0.f?e:NEG*e;
      al=__expf(e-gmax);
    }
    unsigned v = *(const unsigned*)(zb + (size_t)s*256 + 2*t);
    acc0 += al*bf2f(v & 0xffffu);
    acc1 += al*bf2f(v >> 16);
  }
  __syncthreads();
  if (half==1){ s_c[t][0]=acc0; s_c[t][1]=acc1; }
  __syncthreads();
  if (half==0){
    acc0 += s_c[t][0]; acc1 += s_c[t][1];
    *(float2*)(out + (size_t)nd*256 + 2*t) = make_float2(acc0*inv, acc1*inv);
  }
}

// ---------------- launch ----------------
extern "C" void kernel_launch(void* const* d_in, const int* in_sizes, int n_in,
                              void* d_out, int out_size, void* d_ws, size_t ws_size,
                              hipStream_t stream){
  const float* h  = (const float*)d_in[0];
  const float* W1 = (const float*)d_in[1];
  const float* a1 = (const float*)d_in[2];
  const float* W2 = (const float*)d_in[3];
  const float* a2 = (const float*)d_in[4];
  const int* src  = (const int*)d_in[5];
  const int* dst  = (const int*)d_in[6];
  float* out = (float*)d_out;
  int N = in_sizes[0]/256;   // 50000
  int E = in_sizes[5];       // 850000

  char* p=(char*)d_ws;
  auto alloc=[&](size_t bytes)->void*{ void* r=(void*)p; p += (bytes+255)&~(size_t)255; return r; };
  unsigned short* zb  =(unsigned short*)alloc(sizeof(unsigned short)*(size_t)N*256);
  unsigned short* z2b =(unsigned short*)alloc(sizeof(unsigned short)*(size_t)N*256);
  float* h1  =(float*)alloc(sizeof(float)*(size_t)N*256);
  float* es  =(float*)alloc(sizeof(float)*(size_t)N*4);
  float* ed  =(float*)alloc(sizeof(float)*(size_t)N*4);
  float* e2s =(float*)alloc(sizeof(float)*(size_t)N);
  float* e2d =(float*)alloc(sizeof(float)*(size_t)N);
  int* cnt    =(int*)alloc(sizeof(int)*(size_t)N);
  int* row_off=(int*)alloc(sizeof(int)*(size_t)(N+1));
  int* cursor =(int*)alloc(sizeof(int)*(size_t)N);
  int* col    =(int*)alloc(sizeof(int)*(size_t)E);
  int* bsum   =(int*)alloc(sizeof(int)*64);
  int* bpre   =(int*)alloc(sizeof(int)*64);

  int nb = (N+1023)/1024;

  zero_k<<<(N+255)/256,256,0,stream>>>(cnt,e2s,e2d,N);
  hist_k<<<(E+255)/256,256,0,stream>>>(dst,cnt,E);
  scan_partial_k<<<nb,256,0,stream>>>(cnt,bsum,N);
  scan_bsums_k<<<1,64,0,stream>>>(bsum,bpre,nb,row_off,N,E);
  scan_final_k<<<nb,256,0,stream>>>(cnt,bpre,row_off,cursor,N);
  scatter_k<<<(E+255)/256,256,0,stream>>>(src,dst,cursor,col,E);

  dim3 gg((N+63)/64, 4);
  gemm1_k<<<gg,256,0,stream>>>(h,W1,a1,zb,es,ed,N);
  agg1_k<<<N,256,0,stream>>>(zb,es,ed,row_off,col,h1);
  gemm2_k<<<gg,256,0,stream>>>(h1,W2,a2,z2b,e2s,e2d,N);
  agg2_k<<<N,256,0,stream>>>(z2b,e2s,e2d,row_off,col,out);
}

// Round 3
// 472.041 us; speedup vs baseline: 1.4688x; 1.4476x over previous
//
#include <hip/hip_runtime.h>
#include <hip/hip_bf16.h>
#include <math.h>

#define NEG 0.01f
#define MAXDEG 128

// ---------------- helpers ----------------
__device__ __forceinline__ float wmax_all(float v){
#pragma unroll
  for (int o=32;o>0;o>>=1) v = fmaxf(v, __shfl_xor(v,o,64));
  return v;
}
__device__ __forceinline__ float wsum_all(float v){
#pragma unroll
  for (int o=32;o>0;o>>=1) v += __shfl_xor(v,o,64);
  return v;
}
__device__ __forceinline__ int wred_sum_i(int v){
#pragma unroll
  for (int o=32;o>0;o>>=1) v += __shfl_down(v,o,64);
  return v;
}
__device__ __forceinline__ float bf_lo(unsigned u){ union{unsigned i;float f;} c; c.i=u<<16; return c.f; }
__device__ __forceinline__ float bf_hi(unsigned u){ union{unsigned i;float f;} c; c.i=u&0xffff0000u; return c.f; }
__device__ __forceinline__ unsigned short f2bf(float f){
  union{float f; unsigned i;} c; c.f=f;
  unsigned r = c.i + 0x7fffu + ((c.i>>16)&1u);
  return (unsigned short)(r>>16);
}
__device__ __forceinline__ float leaky1(float x){ return x>0.f? x : NEG*x; }

// ---------------- CSR build ----------------
__global__ void zero_k(int* __restrict__ cnt, float* __restrict__ e2s,
                       float* __restrict__ e2d, int n){
  int i = blockIdx.x*blockDim.x + threadIdx.x;
  if (i<n){ cnt[i]=0; e2s[i]=0.f; e2d[i]=0.f; }
}

__global__ void hist_k(const int* __restrict__ dst, int* __restrict__ cnt, int E){
  int i = blockIdx.x*blockDim.x+threadIdx.x;
  if (i<E) atomicAdd(&cnt[dst[i]], 1);
}

__global__ void scan_partial_k(const int* __restrict__ cnt, int* __restrict__ bsum, int n){
  int b = blockIdx.x, t = threadIdx.x;
  int base = b*1024 + t*4;
  int s=0;
#pragma unroll
  for (int i=0;i<4;i++){ int idx=base+i; if(idx<n) s+=cnt[idx]; }
  int ws = wred_sum_i(s);
  __shared__ int sw[4];
  int wave=t>>6, lane=t&63;
  if (lane==0) sw[wave]=ws;
  __syncthreads();
  if (t==0) bsum[b] = sw[0]+sw[1]+sw[2]+sw[3];
}

__global__ void scan_bsums_k(const int* __restrict__ bsum, int* __restrict__ bpre,
                             int nb, int* __restrict__ row_off, int n, int E){
  if (threadIdx.x==0 && blockIdx.x==0){
    int c=0;
    for (int i=0;i<nb;i++){ bpre[i]=c; c+=bsum[i]; }
    row_off[n]=E;
  }
}

__global__ void scan_final_k(const int* __restrict__ cnt, const int* __restrict__ bpre,
                             int* __restrict__ row_off, int* __restrict__ cursor, int n){
  int b=blockIdx.x, t=threadIdx.x;
  int lane=t&63, wave=t>>6;
  int base=b*1024 + t*4;
  int v[4]; int ts=0;
#pragma unroll
  for (int i=0;i<4;i++){ int idx=base+i; v[i]=(idx<n)?cnt[idx]:0; ts+=v[i]; }
  int x=ts;
#pragma unroll
  for (int o=1;o<64;o<<=1){ int y=__shfl_up(x,o,64); if (lane>=o) x+=y; }
  __shared__ int sw[4];
  if (lane==63) sw[wave]=x;
  __syncthreads();
  int wpre=0;
  for (int w=0;w<wave;w++) wpre+=sw[w];
  int run = bpre[b] + wpre + (x - ts);
#pragma unroll
  for (int i=0;i<4;i++){ int idx=base+i; if(idx<n){ row_off[idx]=run; cursor[idx]=run; } run+=v[i]; }
}

__global__ void scatter_k(const int* __restrict__ src, const int* __restrict__ dst,
                          int* __restrict__ cursor, int* __restrict__ col, int E){
  int i=blockIdx.x*blockDim.x+threadIdx.x;
  if (i<E){ int slot=atomicAdd(&cursor[dst[i]],1); col[slot]=src[i]; }
}

// ---------------- GEMM1: z(n x 256) = A @ W1^T, bf16 out + fused es/ed (f32) ----------------
__global__ __launch_bounds__(256) void gemm1_k(const float* __restrict__ A,
      const float* __restrict__ W, const float* __restrict__ a1,
      unsigned short* __restrict__ zb, float* __restrict__ es, float* __restrict__ ed, int n){
  __shared__ float As[32][68];
  __shared__ float Bs[32][68];
  __shared__ float s_es[64][17];
  __shared__ float s_ed[64][17];
  int bm = blockIdx.x*64, bn = blockIdx.y;   // bn = head
  int tid=threadIdx.x, tx=tid&15, ty=tid>>4;
  int lk=tid&31, lr=tid>>5;
  float acc[4][4]={};
  for (int bk=0;bk<256;bk+=32){
#pragma unroll
    for (int rr=0;rr<8;rr++){
      int r=lr+rr*8, gr=bm+r;
      As[lk][r] = (gr<n)? A[(size_t)gr*256+bk+lk] : 0.f;
      Bs[lk][r] = W[(size_t)(bn*64+r)*256 + bk + lk];
    }
    __syncthreads();
#pragma unroll
    for (int k=0;k<32;k++){
      float a[4],b[4];
#pragma unroll
      for (int i=0;i<4;i++) a[i]=As[k][ty*4+i];
#pragma unroll
      for (int j=0;j<4;j++) b[j]=Bs[k][tx*4+j];
#pragma unroll
      for (int i=0;i<4;i++)
#pragma unroll
        for (int j=0;j<4;j++) acc[i][j] += a[i]*b[j];
    }
    __syncthreads();
  }
#pragma unroll
  for (int i=0;i<4;i++){
    int gr=bm+ty*4+i;
    if (gr<n){
      union{ unsigned short u[4]; uint2 v; } pk;
#pragma unroll
      for (int j=0;j<4;j++) pk.u[j]=f2bf(acc[i][j]);
      *(uint2*)(zb + (size_t)gr*256 + bn*64 + tx*4) = pk.v;
    }
  }
  float ws_[4], wd_[4];
#pragma unroll
  for (int j=0;j<4;j++){ ws_[j]=a1[bn*128 + tx*4+j]; wd_[j]=a1[bn*128 + 64 + tx*4+j]; }
#pragma unroll
  for (int i=0;i<4;i++){
    float pe=0.f, pd=0.f;
#pragma unroll
    for (int j=0;j<4;j++){ pe+=acc[i][j]*ws_[j]; pd+=acc[i][j]*wd_[j]; }
    s_es[ty*4+i][tx]=pe; s_ed[ty*4+i][tx]=pd;
  }
  __syncthreads();
  if (tid<64){
    float se=0.f, sd=0.f;
#pragma unroll
    for (int k=0;k<16;k++){ se+=s_es[tid][k]; sd+=s_ed[tid][k]; }
    int gr=bm+tid;
    if (gr<n){ es[gr*4+bn]=se; ed[gr*4+bn]=sd; }
  }
}

// ---------------- GEMM2: z2 = h1 @ W2^T, bf16 out + fused e2s/e2d partials ----------------
__global__ __launch_bounds__(256) void gemm2_k(const float* __restrict__ A,
      const float* __restrict__ W, const float* __restrict__ a2,
      unsigned short* __restrict__ zb, float* __restrict__ e2s, float* __restrict__ e2d, int n){
  __shared__ float As[32][68];
  __shared__ float Bs[32][68];
  __shared__ float s_es[64][17];
  __shared__ float s_ed[64][17];
  int bm = blockIdx.x*64, bn = blockIdx.y;
  int tid=threadIdx.x, tx=tid&15, ty=tid>>4;
  int lk=tid&31, lr=tid>>5;
  float acc[4][4]={};
  for (int bk=0;bk<256;bk+=32){
#pragma unroll
    for (int rr=0;rr<8;rr++){
      int r=lr+rr*8, gr=bm+r;
      As[lk][r] = (gr<n)? A[(size_t)gr*256+bk+lk] : 0.f;
      Bs[lk][r] = W[(size_t)(bn*64+r)*256 + bk + lk];
    }
    __syncthreads();
#pragma unroll
    for (int k=0;k<32;k++){
      float a[4],b[4];
#pragma unroll
      for (int i=0;i<4;i++) a[i]=As[k][ty*4+i];
#pragma unroll
      for (int j=0;j<4;j++) b[j]=Bs[k][tx*4+j];
#pragma unroll
      for (int i=0;i<4;i++)
#pragma unroll
        for (int j=0;j<4;j++) acc[i][j] += a[i]*b[j];
    }
    __syncthreads();
  }
#pragma unroll
  for (int i=0;i<4;i++){
    int gr=bm+ty*4+i;
    if (gr<n){
      union{ unsigned short u[4]; uint2 v; } pk;
#pragma unroll
      for (int j=0;j<4;j++) pk.u[j]=f2bf(acc[i][j]);
      *(uint2*)(zb + (size_t)gr*256 + bn*64 + tx*4) = pk.v;
    }
  }
  float ws_[4], wd_[4];
#pragma unroll
  for (int j=0;j<4;j++){ ws_[j]=a2[bn*64 + tx*4+j]; wd_[j]=a2[256 + bn*64 + tx*4+j]; }
#pragma unroll
  for (int i=0;i<4;i++){
    float pe=0.f, pd=0.f;
#pragma unroll
    for (int j=0;j<4;j++){ pe+=acc[i][j]*ws_[j]; pd+=acc[i][j]*wd_[j]; }
    s_es[ty*4+i][tx]=pe; s_ed[ty*4+i][tx]=pd;
  }
  __syncthreads();
  if (tid<64){
    float se=0.f, sd=0.f;
#pragma unroll
    for (int k=0;k<16;k++){ se+=s_es[tid][k]; sd+=s_ed[tid][k]; }
    int gr=bm+tid;
    if (gr<n){ atomicAdd(&e2s[gr], se); atomicAdd(&e2d[gr], sd); }
  }
}

// ---------------- layer-1: wave-per-dst softmax + aggregate, h1 = elu(m) ----------------
// 4 waves/block, each wave owns one dst node; no __syncthreads.
__global__ __launch_bounds__(256) void agg1_k(const unsigned short* __restrict__ zb,
    const float* __restrict__ es, const float* __restrict__ ed,
    const int* __restrict__ row_off, const int* __restrict__ col,
    float* __restrict__ h1, int n){
  __shared__ int   s_src[4][MAXDEG];
  __shared__ float s_al [4][MAXDEG][4];   // per-edge alpha, head-interleaved
  int w = threadIdx.x>>6, lane = threadIdx.x&63;
  int nd = blockIdx.x*4 + w;
  if (nd>=n) return;
  int beg=row_off[nd], deg=row_off[nd+1]-beg;
  float4 edv = *(const float4*)(ed + (size_t)nd*4);
  float m0=-1e30f,m1=-1e30f,m2=-1e30f,m3=-1e30f;
  for (int j=lane;j<deg;j+=64){
    int s=col[beg+j];
    float4 ev = *((const float4*)es + s);
    ev.x=leaky1(ev.x+edv.x); ev.y=leaky1(ev.y+edv.y);
    ev.z=leaky1(ev.z+edv.z); ev.w=leaky1(ev.w+edv.w);
    if (j<MAXDEG){
      s_src[w][j]=s;
      s_al[w][j][0]=ev.x; s_al[w][j][1]=ev.y; s_al[w][j][2]=ev.z; s_al[w][j][3]=ev.w;
    }
    m0=fmaxf(m0,ev.x); m1=fmaxf(m1,ev.y); m2=fmaxf(m2,ev.z); m3=fmaxf(m3,ev.w);
  }
  m0=wmax_all(m0); m1=wmax_all(m1); m2=wmax_all(m2); m3=wmax_all(m3);
  float t0=0.f,t1=0.f,t2=0.f,t3=0.f;
  for (int j=lane;j<deg;j+=64){
    float e0,e1,e2,e3;
    if (j<MAXDEG){ e0=s_al[w][j][0]; e1=s_al[w][j][1]; e2=s_al[w][j][2]; e3=s_al[w][j][3]; }
    else {
      int s=col[beg+j];
      float4 ev = *((const float4*)es + s);
      e0=leaky1(ev.x+edv.x); e1=leaky1(ev.y+edv.y); e2=leaky1(ev.z+edv.z); e3=leaky1(ev.w+edv.w);
    }
    e0=__expf(e0-m0); e1=__expf(e1-m1); e2=__expf(e2-m2); e3=__expf(e3-m3);
    if (j<MAXDEG){ s_al[w][j][0]=e0; s_al[w][j][1]=e1; s_al[w][j][2]=e2; s_al[w][j][3]=e3; }
    t0+=e0; t1+=e1; t2+=e2; t3+=e3;
  }
  t0=wsum_all(t0); t1=wsum_all(t1); t2=wsum_all(t2); t3=wsum_all(t3);
  int hh = lane>>4;
  float invh = 1.0f/(hh==0? t0 : hh==1? t1 : hh==2? t2 : t3);
  float mh   = (hh==0? m0 : hh==1? m1 : hh==2? m2 : m3);
  // gather: lane owns dims 4*lane..4*lane+3 (uint2 = 4 bf16)
  const uint2* zp = (const uint2*)zb;
  float a0=0.f,a1a=0.f,a2a=0.f,a3=0.f;
  int dm = deg<MAXDEG? deg:MAXDEG;
  int j=0;
  for (; j+2<=dm; j+=2){
    int sA=s_src[w][j], sB=s_src[w][j+1];
    float alA=s_al[w][j][hh], alB=s_al[w][j+1][hh];
    uint2 vA = zp[(size_t)((unsigned)sA*64u + (unsigned)lane)];
    uint2 vB = zp[(size_t)((unsigned)sB*64u + (unsigned)lane)];
    a0 += alA*bf_lo(vA.x); a1a += alA*bf_hi(vA.x);
    a2a += alA*bf_lo(vA.y); a3 += alA*bf_hi(vA.y);
    a0 += alB*bf_lo(vB.x); a1a += alB*bf_hi(vB.x);
    a2a += alB*bf_lo(vB.y); a3 += alB*bf_hi(vB.y);
  }
  for (; j<dm; j++){
    int s=s_src[w][j];
    float al=s_al[w][j][hh];
    uint2 v = zp[(size_t)((unsigned)s*64u + (unsigned)lane)];
    a0 += al*bf_lo(v.x); a1a += al*bf_hi(v.x);
    a2a += al*bf_lo(v.y); a3 += al*bf_hi(v.y);
  }
  for (; j<deg; j++){       // never-taken fallback
    int s=col[beg+j];
    float4 ev = *((const float4*)es + s);
    float e = (hh==0? ev.x+edv.x : hh==1? ev.y+edv.y : hh==2? ev.z+edv.z : ev.w+edv.w);
    float al = __expf(leaky1(e)-mh);
    uint2 v = zp[(size_t)((unsigned)s*64u + (unsigned)lane)];
    a0 += al*bf_lo(v.x); a1a += al*bf_hi(v.x);
    a2a += al*bf_lo(v.y); a3 += al*bf_hi(v.y);
  }
  a0*=invh; a1a*=invh; a2a*=invh; a3*=invh;
  a0 = a0>0.f? a0 : __expf(a0)-1.0f;
  a1a= a1a>0.f? a1a: __expf(a1a)-1.0f;
  a2a= a2a>0.f? a2a: __expf(a2a)-1.0f;
  a3 = a3>0.f? a3 : __expf(a3)-1.0f;
  *((float4*)h1 + (size_t)nd*64 + lane) = make_float4(a0,a1a,a2a,a3);
}

// ---------------- layer-2: wave-per-dst, 1 head, writes out ----------------
__global__ __launch_bounds__(256) void agg2_k(const unsigned short* __restrict__ zb,
    const float* __restrict__ e2s, const float* __restrict__ e2d,
    const int* __restrict__ row_off, const int* __restrict__ col,
    float* __restrict__ out, int n){
  __shared__ int   s_src[4][MAXDEG];
  __shared__ float s_al [4][MAXDEG];
  int w = threadIdx.x>>6, lane = threadIdx.x&63;
  int nd = blockIdx.x*4 + w;
  if (nd>=n) return;
  int beg=row_off[nd], deg=row_off[nd+1]-beg;
  float edv = e2d[nd];
  float m=-1e30f;
  for (int j=lane;j<deg;j+=64){
    int s=col[beg+j];
    float ev = leaky1(e2s[s]+edv);
    if (j<MAXDEG){ s_src[w][j]=s; s_al[w][j]=ev; }
    m=fmaxf(m,ev);
  }
  m=wmax_all(m);
  float ts=0.f;
  for (int j=lane;j<deg;j+=64){
    float e;
    if (j<MAXDEG) e=s_al[w][j];
    else { int s=col[beg+j]; e=leaky1(e2s[s]+edv); }
    e=__expf(e-m);
    if (j<MAXDEG) s_al[w][j]=e;
    ts+=e;
  }
  ts=wsum_all(ts);
  float inv=1.0f/ts;
  const uint2* zp = (const uint2*)zb;
  float a0=0.f,a1a=0.f,a2a=0.f,a3=0.f;
  int dm = deg<MAXDEG? deg:MAXDEG;
  int j=0;
  for (; j+2<=dm; j+=2){
    int sA=s_src[w][j], sB=s_src[w][j+1];
    float alA=s_al[w][j], alB=s_al[w][j+1];
    uint2 vA = zp[(size_t)((unsigned)sA*64u + (unsigned)lane)];
    uint2 vB = zp[(size_t)((unsigned)sB*64u + (unsigned)lane)];
    a0 += alA*bf_lo(vA.x); a1a += alA*bf_hi(vA.x);
    a2a += alA*bf_lo(vA.y); a3 += alA*bf_hi(vA.y);
    a0 += alB*bf_lo(vB.x); a1a += alB*bf_hi(vB.x);
    a2a += alB*bf_lo(vB.y); a3 += alB*bf_hi(vB.y);
  }
  for (; j<dm; j++){
    int s=s_src[w][j];
    float al=s_al[w][j];
    uint2 v = zp[(size_t)((unsigned)s*64u + (unsigned)lane)];
    a0 += al*bf_lo(v.x); a1a += al*bf_hi(v.x);
    a2a += al*bf_lo(v.y); a3 += al*bf_hi(v.y);
  }
  for (; j<deg; j++){
    int s=col[beg+j];
    float al = __expf(leaky1(e2s[s]+edv)-m);
    uint2 v = zp[(size_t)((unsigned)s*64u + (unsigned)lane)];
    a0 += al*bf_lo(v.x); a1a += al*bf_hi(v.x);
    a2a += al*bf_lo(v.y); a3 += al*bf_hi(v.y);
  }
  *((float4*)out + (size_t)nd*64 + lane) = make_float4(a0*inv,a1a*inv,a2a*inv,a3*inv);
}

// ---------------- launch ----------------
extern "C" void kernel_launch(void* const* d_in, const int* in_sizes, int n_in,
                              void* d_out, int out_size, void* d_ws, size_t ws_size,
                              hipStream_t stream){
  const float* h  = (const float*)d_in[0];
  const float* W1 = (const float*)d_in[1];
  const float* a1 = (const float*)d_in[2];
  const float* W2 = (const float*)d_in[3];
  const float* a2 = (const float*)d_in[4];
  const int* src  = (const int*)d_in[5];
  const int* dst  = (const int*)d_in[6];
  float* out = (float*)d_out;
  int N = in_sizes[0]/256;   // 50000
  int E = in_sizes[5];       // 850000

  char* p=(char*)d_ws;
  auto alloc=[&](size_t bytes)->void*{ void* r=(void*)p; p += (bytes+255)&~(size_t)255; return r; };
  unsigned short* zb  =(unsigned short*)alloc(sizeof(unsigned short)*(size_t)N*256);
  unsigned short* z2b =(unsigned short*)alloc(sizeof(unsigned short)*(size_t)N*256);
  float* h1  =(float*)alloc(sizeof(float)*(size_t)N*256);
  float* es  =(float*)alloc(sizeof(float)*(size_t)N*4);
  float* ed  =(float*)alloc(sizeof(float)*(size_t)N*4);
  float* e2s =(float*)alloc(sizeof(float)*(size_t)N);
  float* e2d =(float*)alloc(sizeof(float)*(size_t)N);
  int* cnt    =(int*)alloc(sizeof(int)*(size_t)N);
  int* row_off=(int*)alloc(sizeof(int)*(size_t)(N+1));
  int* cursor =(int*)alloc(sizeof(int)*(size_t)N);
  int* col    =(int*)alloc(sizeof(int)*(size_t)E);
  int* bsum   =(int*)alloc(sizeof(int)*64);
  int* bpre   =(int*)alloc(sizeof(int)*64);

  int nb = (N+1023)/1024;

  zero_k<<<(N+255)/256,256,0,stream>>>(cnt,e2s,e2d,N);
  hist_k<<<(E+255)/256,256,0,stream>>>(dst,cnt,E);
  scan_partial_k<<<nb,256,0,stream>>>(cnt,bsum,N);
  scan_bsums_k<<<1,64,0,stream>>>(bsum,bpre,nb,row_off,N,E);
  scan_final_k<<<nb,256,0,stream>>>(cnt,bpre,row_off,cursor,N);
  scatter_k<<<(E+255)/256,256,0,stream>>>(src,dst,cursor,col,E);

  dim3 gg((N+63)/64, 4);
  gemm1_k<<<gg,256,0,stream>>>(h,W1,a1,zb,es,ed,N);
  agg1_k<<<(N+3)/4,256,0,stream>>>(zb,es,ed,row_off,col,h1,N);
  gemm2_k<<<gg,256,0,stream>>>(h1,W2,a2,z2b,e2s,e2d,N);
  agg2_k<<<(N+3)/4,256,0,stream>>>(z2b,e2s,e2d,row_off,col,out,N);
}

// Round 4
// 358.110 us; speedup vs baseline: 1.9360x; 1.3181x over previous
//
#include <hip/hip_runtime.h>
#include <hip/hip_bf16.h>
#include <math.h>

#define NEG 0.01f
#define MAXDEG 128

typedef __attribute__((ext_vector_type(4))) unsigned u32x4;
typedef __attribute__((ext_vector_type(4))) float f32x4;

// ---------------- helpers ----------------
__device__ __forceinline__ float wmax_all(float v){
#pragma unroll
  for (int o=32;o>0;o>>=1) v = fmaxf(v, __shfl_xor(v,o,64));
  return v;
}
__device__ __forceinline__ float wsum_all(float v){
#pragma unroll
  for (int o=32;o>0;o>>=1) v += __shfl_xor(v,o,64);
  return v;
}
__device__ __forceinline__ int wred_sum_i(int v){
#pragma unroll
  for (int o=32;o>0;o>>=1) v += __shfl_down(v,o,64);
  return v;
}
__device__ __forceinline__ float bf_lo(unsigned u){ union{unsigned i;float f;} c; c.i=u<<16; return c.f; }
__device__ __forceinline__ float bf_hi(unsigned u){ union{unsigned i;float f;} c; c.i=u&0xffff0000u; return c.f; }
__device__ __forceinline__ unsigned short f2bf(float f){
  union{float f; unsigned i;} c; c.f=f;
  unsigned r = c.i + 0x7fffu + ((c.i>>16)&1u);
  return (unsigned short)(r>>16);
}
__device__ __forceinline__ float leaky1(float x){ return x>0.f? x : NEG*x; }

__device__ __forceinline__ void mfma16(f32x4& d, u32x4 a, u32x4 b){
  asm volatile("v_mfma_f32_16x16x32_bf16 %0, %1, %2, %0" : "+v"(d) : "v"(a), "v"(b));
}

// ---------------- CSR build ----------------
__global__ void zero_cnt_k(int* __restrict__ cnt, int n){
  int i = blockIdx.x*blockDim.x + threadIdx.x;
  if (i<n) cnt[i]=0;
}

__global__ void hist_k(const int* __restrict__ dst, int* __restrict__ cnt, int E){
  int i = blockIdx.x*blockDim.x+threadIdx.x;
  if (i<E) atomicAdd(&cnt[dst[i]], 1);
}

__global__ void scan_partial_k(const int* __restrict__ cnt, int* __restrict__ bsum, int n){
  int b = blockIdx.x, t = threadIdx.x;
  int base = b*1024 + t*4;
  int s=0;
#pragma unroll
  for (int i=0;i<4;i++){ int idx=base+i; if(idx<n) s+=cnt[idx]; }
  int ws = wred_sum_i(s);
  __shared__ int sw[4];
  int wave=t>>6, lane=t&63;
  if (lane==0) sw[wave]=ws;
  __syncthreads();
  if (t==0) bsum[b] = sw[0]+sw[1]+sw[2]+sw[3];
}

__global__ void scan_bsums_k(const int* __restrict__ bsum, int* __restrict__ bpre,
                             int nb, int* __restrict__ row_off, int n, int E){
  if (threadIdx.x==0 && blockIdx.x==0){
    int c=0;
    for (int i=0;i<nb;i++){ bpre[i]=c; c+=bsum[i]; }
    row_off[n]=E;
  }
}

__global__ void scan_final_k(const int* __restrict__ cnt, const int* __restrict__ bpre,
                             int* __restrict__ row_off, int* __restrict__ cursor, int n){
  int b=blockIdx.x, t=threadIdx.x;
  int lane=t&63, wave=t>>6;
  int base=b*1024 + t*4;
  int v[4]; int ts=0;
#pragma unroll
  for (int i=0;i<4;i++){ int idx=base+i; v[i]=(idx<n)?cnt[idx]:0; ts+=v[i]; }
  int x=ts;
#pragma unroll
  for (int o=1;o<64;o<<=1){ int y=__shfl_up(x,o,64); if (lane>=o) x+=y; }
  __shared__ int sw[4];
  if (lane==63) sw[wave]=x;
  __syncthreads();
  int wpre=0;
  for (int w=0;w<wave;w++) wpre+=sw[w];
  int run = bpre[b] + wpre + (x - ts);
#pragma unroll
  for (int i=0;i<4;i++){ int idx=base+i; if(idx<n){ row_off[idx]=run; cursor[idx]=run; } run+=v[i]; }
}

__global__ void scatter_k(const int* __restrict__ src, const int* __restrict__ dst,
                          int* __restrict__ cursor, int* __restrict__ col, int E){
  int i=blockIdx.x*blockDim.x+threadIdx.x;
  if (i<E){ int slot=atomicAdd(&cursor[dst[i]],1); col[slot]=src[i]; }
}

// ---------------- converts ----------------
__global__ void conv_h_k(const float* __restrict__ h, unsigned short* __restrict__ Ab,
                         int n_elems, int npad_elems){
  int i = blockIdx.x*blockDim.x + threadIdx.x;
  int base = i*8;
  if (base >= npad_elems) return;
  unsigned short u[8];
  if (base + 8 <= n_elems){
    float4 x = *(const float4*)(h+base);
    float4 y = *(const float4*)(h+base+4);
    u[0]=f2bf(x.x);u[1]=f2bf(x.y);u[2]=f2bf(x.z);u[3]=f2bf(x.w);
    u[4]=f2bf(y.x);u[5]=f2bf(y.y);u[6]=f2bf(y.z);u[7]=f2bf(y.w);
  } else {
#pragma unroll
    for (int j=0;j<8;j++) u[j]=0;
  }
  uint4 o;
  o.x=(unsigned)u[0]|((unsigned)u[1]<<16); o.y=(unsigned)u[2]|((unsigned)u[3]<<16);
  o.z=(unsigned)u[4]|((unsigned)u[5]<<16); o.w=(unsigned)u[6]|((unsigned)u[7]<<16);
  *(uint4*)(Ab+base)=o;
}

__global__ void conv_w_k(const float* __restrict__ W1, const float* __restrict__ W2,
                         unsigned short* __restrict__ Wb){
  int i = blockIdx.x*blockDim.x + threadIdx.x;   // 16384 threads, 8 elems each
  int base = i*8;
  const float* src = (base<65536)? (W1+base) : (W2+(base-65536));
  float4 x=*(const float4*)src, y=*(const float4*)(src+4);
  unsigned short u[8];
  u[0]=f2bf(x.x);u[1]=f2bf(x.y);u[2]=f2bf(x.z);u[3]=f2bf(x.w);
  u[4]=f2bf(y.x);u[5]=f2bf(y.y);u[6]=f2bf(y.z);u[7]=f2bf(y.w);
  uint4 o;
  o.x=(unsigned)u[0]|((unsigned)u[1]<<16); o.y=(unsigned)u[2]|((unsigned)u[3]<<16);
  o.z=(unsigned)u[4]|((unsigned)u[5]<<16); o.w=(unsigned)u[6]|((unsigned)u[7]<<16);
  *(uint4*)(Wb+base)=o;
}

// ---------------- MFMA GEMM: C(Npad x 256) = A(Npad x 256,bf16) @ W(256 x 256,bf16)^T --------
// BM=64, BN=256 (one block spans all cols; A read once), BK=64, 4 waves (wave = 64-col quadrant)
// Fused epilogue: z bf16 + es/ed (L==1: per-wave head; L==2: cross-wave LDS reduce)
template<int L>
__global__ __launch_bounds__(256) void gemm_mfma(const unsigned short* __restrict__ Ab,
    const unsigned short* __restrict__ Wb, const float* __restrict__ av,
    unsigned short* __restrict__ zb, float* __restrict__ eS, float* __restrict__ eD){
  __shared__ char lds[40960];            // A: [64][64]bf16 8KB | B: [256][64]bf16 32KB @8192
  const int tid=threadIdx.x, lane=tid&63, w=tid>>6;
  const int r15=lane&15, kg=lane>>4;
  const int bm = blockIdx.x*64;
  const char* Ag = (const char*)Ab + (size_t)bm*512;   // row stride 512B
  const char* Bg = (const char*)Wb;
  uint4 rg[10];
  auto gload=[&](int kt){
#pragma unroll
    for (int i=0;i<2;i++){
      int o=tid*16+i*4096, row=o>>7, cb=o&127;
      rg[i] = *(const uint4*)(Ag + (size_t)row*512 + kt*128 + cb);
    }
#pragma unroll
    for (int i=0;i<8;i++){
      int o=tid*16+i*4096, row=o>>7, cb=o&127;
      rg[2+i] = *(const uint4*)(Bg + (size_t)row*512 + kt*128 + cb);
    }
  };
  auto dswrite=[&](){
#pragma unroll
    for (int i=0;i<2;i++){
      int o=tid*16+i*4096, row=o>>7;
      *(uint4*)(lds + (o ^ ((row&7)<<4))) = rg[i];
    }
#pragma unroll
    for (int i=0;i<8;i++){
      int o=tid*16+i*4096, row=o>>7;
      *(uint4*)(lds + 8192 + (o ^ ((row&7)<<4))) = rg[2+i];
    }
  };
  f32x4 acc[4][4];
  f32x4 z4 = {0.f,0.f,0.f,0.f};
#pragma unroll
  for (int m=0;m<4;m++)
#pragma unroll
    for (int n=0;n<4;n++) acc[m][n]=z4;

  gload(0); dswrite(); __syncthreads();
  for (int kt=0;kt<4;kt++){
    if (kt<3) gload(kt+1);             // issue-early: HBM latency hides under MFMAs
#pragma unroll
    for (int kk=0;kk<2;kk++){
      u32x4 af[4], bf[4];
#pragma unroll
      for (int m=0;m<4;m++){
        int row = m*16 + r15;
        int off = row*128 + kk*64 + kg*16;
        af[m] = *(const u32x4*)(lds + (off ^ ((row&7)<<4)));
      }
#pragma unroll
      for (int n=0;n<4;n++){
        int c = w*64 + n*16 + r15;
        int off = c*128 + kk*64 + kg*16;
        bf[n] = *(const u32x4*)(lds + 8192 + (off ^ ((c&7)<<4)));
      }
#pragma unroll
      for (int m=0;m<4;m++)
#pragma unroll
        for (int n=0;n<4;n++) mfma16(acc[m][n], af[m], bf[n]);
    }
    __syncthreads();
    if (kt<3){ dswrite(); __syncthreads(); }
  }
  asm volatile("s_nop 7\n\ts_nop 7");   // MFMA->VALU read spacing
  // ---- es/ed epilogue ----
  float avs[4], avd[4];
#pragma unroll
  for (int n=0;n<4;n++){
    int c = n*16 + r15;
    if (L==1){ avs[n]=av[w*128 + c];      avd[n]=av[w*128 + 64 + c]; }
    else     { avs[n]=av[w*64 + c];       avd[n]=av[256 + w*64 + c]; }
  }
  __syncthreads();                       // safe LDS reuse
  float* s_ep = (float*)lds;             // [4][64][2]
#pragma unroll
  for (int m=0;m<4;m++)
#pragma unroll
    for (int j=0;j<4;j++){
      float pe=0.f, pd=0.f;
#pragma unroll
      for (int n=0;n<4;n++){ pe += acc[m][n][j]*avs[n]; pd += acc[m][n][j]*avd[n]; }
#pragma unroll
      for (int o=1;o<16;o<<=1){ pe += __shfl_xor(pe,o,64); pd += __shfl_xor(pd,o,64); }
      if (r15==0){
        int lrow = m*16 + kg*4 + j;
        if (L==1){ eS[(size_t)(bm+lrow)*4 + w]=pe; eD[(size_t)(bm+lrow)*4 + w]=pd; }
        else     { s_ep[(w*64+lrow)*2]=pe; s_ep[(w*64+lrow)*2+1]=pd; }
      }
    }
  if (L==2){
    __syncthreads();
    if (tid<64){
      float se = s_ep[(0*64+tid)*2]+s_ep[(1*64+tid)*2]+s_ep[(2*64+tid)*2]+s_ep[(3*64+tid)*2];
      float sd = s_ep[(0*64+tid)*2+1]+s_ep[(1*64+tid)*2+1]+s_ep[(2*64+tid)*2+1]+s_ep[(3*64+tid)*2+1];
      eS[bm+tid]=se; eD[bm+tid]=sd;
    }
  }
  // ---- z bf16 write (pair-pack via shfl) ----
#pragma unroll
  for (int m=0;m<4;m++)
#pragma unroll
    for (int n=0;n<4;n++)
#pragma unroll
      for (int j=0;j<4;j++){
        float v0 = acc[m][n][j];
        float v1 = __shfl_down(v0,1,64);
        if (!(lane&1)){
          unsigned pk = (unsigned)f2bf(v0) | ((unsigned)f2bf(v1)<<16);
          int row = bm + m*16 + kg*4 + j, cc = w*64 + n*16 + r15;
          *(unsigned*)(zb + (size_t)row*256 + cc) = pk;
        }
      }
}

// ---------------- layer-1: wave-per-dst softmax + aggregate, h1 = elu(m) (bf16 out) ----------
__global__ __launch_bounds__(256) void agg1_k(const unsigned short* __restrict__ zb,
    const float* __restrict__ es, const float* __restrict__ ed,
    const int* __restrict__ row_off, const int* __restrict__ col,
    unsigned short* __restrict__ h1b, int n){
  __shared__ int   s_src[4][MAXDEG];
  __shared__ float s_al [4][MAXDEG][4];
  int w = threadIdx.x>>6, lane = threadIdx.x&63;
  int nd = blockIdx.x*4 + w;
  if (nd>=n) return;
  int beg=row_off[nd], deg=row_off[nd+1]-beg;
  float4 edv = *(const float4*)(ed + (size_t)nd*4);
  float m0=-1e30f,m1=-1e30f,m2=-1e30f,m3=-1e30f;
  for (int j=lane;j<deg;j+=64){
    int s=col[beg+j];
    float4 ev = *((const float4*)es + s);
    ev.x=leaky1(ev.x+edv.x); ev.y=leaky1(ev.y+edv.y);
    ev.z=leaky1(ev.z+edv.z); ev.w=leaky1(ev.w+edv.w);
    if (j<MAXDEG){
      s_src[w][j]=s;
      s_al[w][j][0]=ev.x; s_al[w][j][1]=ev.y; s_al[w][j][2]=ev.z; s_al[w][j][3]=ev.w;
    }
    m0=fmaxf(m0,ev.x); m1=fmaxf(m1,ev.y); m2=fmaxf(m2,ev.z); m3=fmaxf(m3,ev.w);
  }
  m0=wmax_all(m0); m1=wmax_all(m1); m2=wmax_all(m2); m3=wmax_all(m3);
  float t0=0.f,t1=0.f,t2=0.f,t3=0.f;
  for (int j=lane;j<deg;j+=64){
    float e0,e1,e2,e3;
    if (j<MAXDEG){ e0=s_al[w][j][0]; e1=s_al[w][j][1]; e2=s_al[w][j][2]; e3=s_al[w][j][3]; }
    else {
      int s=col[beg+j];
      float4 ev = *((const float4*)es + s);
      e0=leaky1(ev.x+edv.x); e1=leaky1(ev.y+edv.y); e2=leaky1(ev.z+edv.z); e3=leaky1(ev.w+edv.w);
    }
    e0=__expf(e0-m0); e1=__expf(e1-m1); e2=__expf(e2-m2); e3=__expf(e3-m3);
    if (j<MAXDEG){ s_al[w][j][0]=e0; s_al[w][j][1]=e1; s_al[w][j][2]=e2; s_al[w][j][3]=e3; }
    t0+=e0; t1+=e1; t2+=e2; t3+=e3;
  }
  t0=wsum_all(t0); t1=wsum_all(t1); t2=wsum_all(t2); t3=wsum_all(t3);
  int hh = lane>>4;
  float invh = 1.0f/(hh==0? t0 : hh==1? t1 : hh==2? t2 : t3);
  float mh   = (hh==0? m0 : hh==1? m1 : hh==2? m2 : m3);
  const uint2* zp = (const uint2*)zb;
  float a0=0.f,a1a=0.f,a2a=0.f,a3=0.f;
  int dm = deg<MAXDEG? deg:MAXDEG;
  int j=0;
  for (; j+2<=dm; j+=2){
    int sA=s_src[w][j], sB=s_src[w][j+1];
    float alA=s_al[w][j][hh], alB=s_al[w][j+1][hh];
    uint2 vA = zp[(size_t)((unsigned)sA*64u + (unsigned)lane)];
    uint2 vB = zp[(size_t)((unsigned)sB*64u + (unsigned)lane)];
    a0 += alA*bf_lo(vA.x); a1a += alA*bf_hi(vA.x);
    a2a += alA*bf_lo(vA.y); a3 += alA*bf_hi(vA.y);
    a0 += alB*bf_lo(vB.x); a1a += alB*bf_hi(vB.x);
    a2a += alB*bf_lo(vB.y); a3 += alB*bf_hi(vB.y);
  }
  for (; j<dm; j++){
    int s=s_src[w][j];
    float al=s_al[w][j][hh];
    uint2 v = zp[(size_t)((unsigned)s*64u + (unsigned)lane)];
    a0 += al*bf_lo(v.x); a1a += al*bf_hi(v.x);
    a2a += al*bf_lo(v.y); a3 += al*bf_hi(v.y);
  }
  for (; j<deg; j++){
    int s=col[beg+j];
    float4 ev = *((const float4*)es + s);
    float e = (hh==0? ev.x+edv.x : hh==1? ev.y+edv.y : hh==2? ev.z+edv.z : ev.w+edv.w);
    float al = __expf(leaky1(e)-mh);
    uint2 v = zp[(size_t)((unsigned)s*64u + (unsigned)lane)];
    a0 += al*bf_lo(v.x); a1a += al*bf_hi(v.x);
    a2a += al*bf_lo(v.y); a3 += al*bf_hi(v.y);
  }
  a0*=invh; a1a*=invh; a2a*=invh; a3*=invh;
  a0 = a0>0.f? a0 : __expf(a0)-1.0f;
  a1a= a1a>0.f? a1a: __expf(a1a)-1.0f;
  a2a= a2a>0.f? a2a: __expf(a2a)-1.0f;
  a3 = a3>0.f? a3 : __expf(a3)-1.0f;
  unsigned lo = (unsigned)f2bf(a0) | ((unsigned)f2bf(a1a)<<16);
  unsigned hi = (unsigned)f2bf(a2a) | ((unsigned)f2bf(a3)<<16);
  *(uint2*)(h1b + (size_t)nd*256 + lane*4) = make_uint2(lo,hi);
}

// ---------------- layer-2: wave-per-dst, 1 head, writes out (f32) ----------------
__global__ __launch_bounds__(256) void agg2_k(const unsigned short* __restrict__ zb,
    const float* __restrict__ e2s, const float* __restrict__ e2d,
    const int* __restrict__ row_off, const int* __restrict__ col,
    float* __restrict__ out, int n){
  __shared__ int   s_src[4][MAXDEG];
  __shared__ float s_al [4][MAXDEG];
  int w = threadIdx.x>>6, lane = threadIdx.x&63;
  int nd = blockIdx.x*4 + w;
  if (nd>=n) return;
  int beg=row_off[nd], deg=row_off[nd+1]-beg;
  float edv = e2d[nd];
  float m=-1e30f;
  for (int j=lane;j<deg;j+=64){
    int s=col[beg+j];
    float ev = leaky1(e2s[s]+edv);
    if (j<MAXDEG){ s_src[w][j]=s; s_al[w][j]=ev; }
    m=fmaxf(m,ev);
  }
  m=wmax_all(m);
  float ts=0.f;
  for (int j=lane;j<deg;j+=64){
    float e;
    if (j<MAXDEG) e=s_al[w][j];
    else { int s=col[beg+j]; e=leaky1(e2s[s]+edv); }
    e=__expf(e-m);
    if (j<MAXDEG) s_al[w][j]=e;
    ts+=e;
  }
  ts=wsum_all(ts);
  float inv=1.0f/ts;
  const uint2* zp = (const uint2*)zb;
  float a0=0.f,a1a=0.f,a2a=0.f,a3=0.f;
  int dm = deg<MAXDEG? deg:MAXDEG;
  int j=0;
  for (; j+2<=dm; j+=2){
    int sA=s_src[w][j], sB=s_src[w][j+1];
    float alA=s_al[w][j], alB=s_al[w][j+1];
    uint2 vA = zp[(size_t)((unsigned)sA*64u + (unsigned)lane)];
    uint2 vB = zp[(size_t)((unsigned)sB*64u + (unsigned)lane)];
    a0 += alA*bf_lo(vA.x); a1a += alA*bf_hi(vA.x);
    a2a += alA*bf_lo(vA.y); a3 += alA*bf_hi(vA.y);
    a0 += alB*bf_lo(vB.x); a1a += alB*bf_hi(vB.x);
    a2a += alB*bf_lo(vB.y); a3 += alB*bf_hi(vB.y);
  }
  for (; j<dm; j++){
    int s=s_src[w][j];
    float al=s_al[w][j];
    uint2 v = zp[(size_t)((unsigned)s*64u + (unsigned)lane)];
    a0 += al*bf_lo(v.x); a1a += al*bf_hi(v.x);
    a2a += al*bf_lo(v.y); a3 += al*bf_hi(v.y);
  }
  for (; j<deg; j++){
    int s=col[beg+j];
    float al = __expf(leaky1(e2s[s]+edv)-m);
    uint2 v = zp[(size_t)((unsigned)s*64u + (unsigned)lane)];
    a0 += al*bf_lo(v.x); a1a += al*bf_hi(v.x);
    a2a += al*bf_lo(v.y); a3 += al*bf_hi(v.y);
  }
  *((float4*)out + (size_t)nd*64 + lane) = make_float4(a0*inv,a1a*inv,a2a*inv,a3*inv);
}

// ---------------- launch ----------------
extern "C" void kernel_launch(void* const* d_in, const int* in_sizes, int n_in,
                              void* d_out, int out_size, void* d_ws, size_t ws_size,
                              hipStream_t stream){
  const float* h  = (const float*)d_in[0];
  const float* W1 = (const float*)d_in[1];
  const float* a1 = (const float*)d_in[2];
  const float* W2 = (const float*)d_in[3];
  const float* a2 = (const float*)d_in[4];
  const int* src  = (const int*)d_in[5];
  const int* dst  = (const int*)d_in[6];
  float* out = (float*)d_out;
  int N = in_sizes[0]/256;          // 50000
  int E = in_sizes[5];              // 850000
  int Npad = ((N+63)/64)*64;        // 50048

  char* p=(char*)d_ws;
  auto alloc=[&](size_t bytes)->void*{ void* r=(void*)p; p += (bytes+255)&~(size_t)255; return r; };
  unsigned short* Ab  =(unsigned short*)alloc(sizeof(unsigned short)*(size_t)Npad*256);
  unsigned short* zb  =(unsigned short*)alloc(sizeof(unsigned short)*(size_t)Npad*256);
  unsigned short* z2b =(unsigned short*)alloc(sizeof(unsigned short)*(size_t)Npad*256);
  unsigned short* h1b =(unsigned short*)alloc(sizeof(unsigned short)*(size_t)Npad*256);
  unsigned short* Wb  =(unsigned short*)alloc(sizeof(unsigned short)*131072);
  float* es  =(float*)alloc(sizeof(float)*(size_t)Npad*4);
  float* ed  =(float*)alloc(sizeof(float)*(size_t)Npad*4);
  float* e2s =(float*)alloc(sizeof(float)*(size_t)Npad);
  float* e2d =(float*)alloc(sizeof(float)*(size_t)Npad);
  int* cnt    =(int*)alloc(sizeof(int)*(size_t)N);
  int* row_off=(int*)alloc(sizeof(int)*(size_t)(N+1));
  int* cursor =(int*)alloc(sizeof(int)*(size_t)N);
  int* col    =(int*)alloc(sizeof(int)*(size_t)E);
  int* bsum   =(int*)alloc(sizeof(int)*64);
  int* bpre   =(int*)alloc(sizeof(int)*64);

  int nb = (N+1023)/1024;

  zero_cnt_k<<<(N+255)/256,256,0,stream>>>(cnt,N);
  hist_k<<<(E+255)/256,256,0,stream>>>(dst,cnt,E);
  scan_partial_k<<<nb,256,0,stream>>>(cnt,bsum,N);
  scan_bsums_k<<<1,64,0,stream>>>(bsum,bpre,nb,row_off,N,E);
  scan_final_k<<<nb,256,0,stream>>>(cnt,bpre,row_off,cursor,N);
  scatter_k<<<(E+255)/256,256,0,stream>>>(src,dst,cursor,col,E);

  conv_h_k<<<(Npad*32+255)/256,256,0,stream>>>(h,Ab,N*256,Npad*256);
  conv_w_k<<<64,256,0,stream>>>(W1,W2,Wb);

  int gblocks = Npad/64;
  gemm_mfma<1><<<gblocks,256,0,stream>>>(Ab, Wb, a1, zb, es, ed);
  agg1_k<<<(N+3)/4,256,0,stream>>>(zb,es,ed,row_off,col,h1b,N);
  gemm_mfma<2><<<gblocks,256,0,stream>>>(h1b, Wb+65536, a2, z2b, e2s, e2d);
  agg2_k<<<(N+3)/4,256,0,stream>>>(z2b,e2s,e2d,row_off,col,out,N);
}

// Round 5
// 299.019 us; speedup vs baseline: 2.3186x; 1.1976x over previous
//
#include <hip/hip_runtime.h>
#include <hip/hip_bf16.h>
#include <math.h>

#define NEG 0.01f
#define MAXDEG 128

typedef __attribute__((ext_vector_type(4))) unsigned u32x4;
typedef __attribute__((ext_vector_type(4))) float f32x4;

// ---------------- helpers ----------------
__device__ __forceinline__ float wmax_all(float v){
#pragma unroll
  for (int o=32;o>0;o>>=1) v = fmaxf(v, __shfl_xor(v,o,64));
  return v;
}
__device__ __forceinline__ float wsum_all(float v){
#pragma unroll
  for (int o=32;o>0;o>>=1) v += __shfl_xor(v,o,64);
  return v;
}
__device__ __forceinline__ int wred_sum_i(int v){
#pragma unroll
  for (int o=32;o>0;o>>=1) v += __shfl_down(v,o,64);
  return v;
}
__device__ __forceinline__ float bf_lo(unsigned u){ union{unsigned i;float f;} c; c.i=u<<16; return c.f; }
__device__ __forceinline__ float bf_hi(unsigned u){ union{unsigned i;float f;} c; c.i=u&0xffff0000u; return c.f; }
__device__ __forceinline__ unsigned short f2bf(float f){
  union{float f; unsigned i;} c; c.f=f;
  unsigned r = c.i + 0x7fffu + ((c.i>>16)&1u);
  return (unsigned short)(r>>16);
}
__device__ __forceinline__ float leaky1(float x){ return x>0.f? x : NEG*x; }

__device__ __forceinline__ void mfma16(f32x4& d, u32x4 a, u32x4 b){
  asm volatile("v_mfma_f32_16x16x32_bf16 %0, %1, %2, %0" : "+v"(d) : "v"(a), "v"(b));
}

// ---------------- CSR build ----------------
__global__ void zero_cnt_k(int* __restrict__ cnt, int n){
  int i = blockIdx.x*blockDim.x + threadIdx.x;
  if (i<n) cnt[i]=0;
}

__global__ void hist_k(const int* __restrict__ dst, int* __restrict__ cnt, int E){
  int i = blockIdx.x*blockDim.x+threadIdx.x;
  if (i<E) atomicAdd(&cnt[dst[i]], 1);
}

__global__ void scan_partial_k(const int* __restrict__ cnt, int* __restrict__ bsum, int n){
  int b = blockIdx.x, t = threadIdx.x;
  int base = b*1024 + t*4;
  int s=0;
#pragma unroll
  for (int i=0;i<4;i++){ int idx=base+i; if(idx<n) s+=cnt[idx]; }
  int ws = wred_sum_i(s);
  __shared__ int sw[4];
  int wave=t>>6, lane=t&63;
  if (lane==0) sw[wave]=ws;
  __syncthreads();
  if (t==0) bsum[b] = sw[0]+sw[1]+sw[2]+sw[3];
}

__global__ void scan_bsums_k(const int* __restrict__ bsum, int* __restrict__ bpre,
                             int nb, int* __restrict__ row_off, int n, int E){
  if (threadIdx.x==0 && blockIdx.x==0){
    int c=0;
    for (int i=0;i<nb;i++){ bpre[i]=c; c+=bsum[i]; }
    row_off[n]=E;
  }
}

__global__ void scan_final_k(const int* __restrict__ cnt, const int* __restrict__ bpre,
                             int* __restrict__ row_off, int* __restrict__ cursor, int n){
  int b=blockIdx.x, t=threadIdx.x;
  int lane=t&63, wave=t>>6;
  int base=b*1024 + t*4;
  int v[4]; int ts=0;
#pragma unroll
  for (int i=0;i<4;i++){ int idx=base+i; v[i]=(idx<n)?cnt[idx]:0; ts+=v[i]; }
  int x=ts;
#pragma unroll
  for (int o=1;o<64;o<<=1){ int y=__shfl_up(x,o,64); if (lane>=o) x+=y; }
  __shared__ int sw[4];
  if (lane==63) sw[wave]=x;
  __syncthreads();
  int wpre=0;
  for (int w=0;w<wave;w++) wpre+=sw[w];
  int run = bpre[b] + wpre + (x - ts);
#pragma unroll
  for (int i=0;i<4;i++){ int idx=base+i; if(idx<n){ row_off[idx]=run; cursor[idx]=run; } run+=v[i]; }
}

__global__ void scatter_k(const int* __restrict__ src, const int* __restrict__ dst,
                          int* __restrict__ cursor, int* __restrict__ col, int E){
  int i=blockIdx.x*blockDim.x+threadIdx.x;
  if (i<E){ int slot=atomicAdd(&cursor[dst[i]],1); col[slot]=src[i]; }
}

// ---------------- converts ----------------
__global__ void conv_h_k(const float* __restrict__ h, unsigned short* __restrict__ Ab,
                         int n_elems, int npad_elems){
  int i = blockIdx.x*blockDim.x + threadIdx.x;
  int base = i*8;
  if (base >= npad_elems) return;
  unsigned short u[8];
  if (base + 8 <= n_elems){
    float4 x = *(const float4*)(h+base);
    float4 y = *(const float4*)(h+base+4);
    u[0]=f2bf(x.x);u[1]=f2bf(x.y);u[2]=f2bf(x.z);u[3]=f2bf(x.w);
    u[4]=f2bf(y.x);u[5]=f2bf(y.y);u[6]=f2bf(y.z);u[7]=f2bf(y.w);
  } else {
#pragma unroll
    for (int j=0;j<8;j++) u[j]=0;
  }
  uint4 o;
  o.x=(unsigned)u[0]|((unsigned)u[1]<<16); o.y=(unsigned)u[2]|((unsigned)u[3]<<16);
  o.z=(unsigned)u[4]|((unsigned)u[5]<<16); o.w=(unsigned)u[6]|((unsigned)u[7]<<16);
  *(uint4*)(Ab+base)=o;
}

__global__ void conv_w_k(const float* __restrict__ W1, const float* __restrict__ W2,
                         unsigned short* __restrict__ Wb){
  int i = blockIdx.x*blockDim.x + threadIdx.x;   // 16384 threads, 8 elems each
  int base = i*8;
  const float* src = (base<65536)? (W1+base) : (W2+(base-65536));
  float4 x=*(const float4*)src, y=*(const float4*)(src+4);
  unsigned short u[8];
  u[0]=f2bf(x.x);u[1]=f2bf(x.y);u[2]=f2bf(x.z);u[3]=f2bf(x.w);
  u[4]=f2bf(y.x);u[5]=f2bf(y.y);u[6]=f2bf(y.z);u[7]=f2bf(y.w);
  uint4 o;
  o.x=(unsigned)u[0]|((unsigned)u[1]<<16); o.y=(unsigned)u[2]|((unsigned)u[3]<<16);
  o.z=(unsigned)u[4]|((unsigned)u[5]<<16); o.w=(unsigned)u[6]|((unsigned)u[7]<<16);
  *(uint4*)(Wb+base)=o;
}

// ---------------- MFMA GEMM: C(Npad x 256) = A(Npad x 256,bf16) @ W(256 x 256,bf16)^T --------
// BM=64, BN=256 (one block spans all cols; A read once), BK=64, 4 waves (wave = 64-col quadrant)
// Staging: load->immediate swizzled LDS write (short reg live range; no spill).
// Fused epilogue: z bf16 + es/ed (L==1: per-wave head; L==2: cross-wave LDS reduce)
template<int L>
__global__ __launch_bounds__(256) void gemm_mfma(const unsigned short* __restrict__ Ab,
    const unsigned short* __restrict__ Wb, const float* __restrict__ av,
    unsigned short* __restrict__ zb, float* __restrict__ eS, float* __restrict__ eD){
  __shared__ char lds[40960];            // A: [64][64]bf16 8KB | B: [256][64]bf16 32KB @8192
  const int tid=threadIdx.x, lane=tid&63, w=tid>>6;
  const int r15=lane&15, kg=lane>>4;
  const int bm = blockIdx.x*64;
  const char* Ag = (const char*)Ab + (size_t)bm*512;   // row stride 512B
  const char* Bg = (const char*)Wb;
  auto stage=[&](int kt){
#pragma unroll
    for (int i=0;i<2;i++){
      int o=tid*16+i*4096, row=o>>7, cb=o&127;
      uint4 v = *(const uint4*)(Ag + (size_t)row*512 + kt*128 + cb);
      *(uint4*)(lds + (o ^ ((row&7)<<4))) = v;
    }
#pragma unroll
    for (int i=0;i<8;i++){
      int o=tid*16+i*4096, row=o>>7, cb=o&127;
      uint4 v = *(const uint4*)(Bg + (size_t)row*512 + kt*128 + cb);
      *(uint4*)(lds + 8192 + (o ^ ((row&7)<<4))) = v;
    }
  };
  f32x4 acc[4][4];
  f32x4 z4 = {0.f,0.f,0.f,0.f};
#pragma unroll
  for (int m=0;m<4;m++)
#pragma unroll
    for (int n=0;n<4;n++) acc[m][n]=z4;

  for (int kt=0;kt<4;kt++){
    if (kt) __syncthreads();           // prior tile's reads done before overwrite
    stage(kt);
    __syncthreads();
#pragma unroll
    for (int kk=0;kk<2;kk++){
      u32x4 af[4], bf[4];
#pragma unroll
      for (int m=0;m<4;m++){
        int row = m*16 + r15;
        int off = row*128 + kk*64 + kg*16;
        af[m] = *(const u32x4*)(lds + (off ^ ((row&7)<<4)));
      }
#pragma unroll
      for (int n=0;n<4;n++){
        int c = w*64 + n*16 + r15;
        int off = c*128 + kk*64 + kg*16;
        bf[n] = *(const u32x4*)(lds + 8192 + (off ^ ((c&7)<<4)));
      }
#pragma unroll
      for (int m=0;m<4;m++)
#pragma unroll
        for (int n=0;n<4;n++) mfma16(acc[m][n], af[m], bf[n]);
    }
  }
  asm volatile("s_nop 7\n\ts_nop 7");   // MFMA->VALU read spacing
  // ---- es/ed epilogue ----
  float avs[4], avd[4];
#pragma unroll
  for (int n=0;n<4;n++){
    int c = n*16 + r15;
    if (L==1){ avs[n]=av[w*128 + c];      avd[n]=av[w*128 + 64 + c]; }
    else     { avs[n]=av[w*64 + c];       avd[n]=av[256 + w*64 + c]; }
  }
  __syncthreads();                       // all ds_reads of tile data complete -> safe LDS reuse
  float* s_ep = (float*)lds;             // [4][64][2]
#pragma unroll
  for (int m=0;m<4;m++)
#pragma unroll
    for (int j=0;j<4;j++){
      float pe=0.f, pd=0.f;
#pragma unroll
      for (int n=0;n<4;n++){ pe += acc[m][n][j]*avs[n]; pd += acc[m][n][j]*avd[n]; }
#pragma unroll
      for (int o=1;o<16;o<<=1){ pe += __shfl_xor(pe,o,64); pd += __shfl_xor(pd,o,64); }
      if (r15==0){
        int lrow = m*16 + kg*4 + j;
        if (L==1){ eS[(size_t)(bm+lrow)*4 + w]=pe; eD[(size_t)(bm+lrow)*4 + w]=pd; }
        else     { s_ep[(w*64+lrow)*2]=pe; s_ep[(w*64+lrow)*2+1]=pd; }
      }
    }
  if (L==2){
    __syncthreads();
    if (tid<64){
      float se = s_ep[(0*64+tid)*2]+s_ep[(1*64+tid)*2]+s_ep[(2*64+tid)*2]+s_ep[(3*64+tid)*2];
      float sd = s_ep[(0*64+tid)*2+1]+s_ep[(1*64+tid)*2+1]+s_ep[(2*64+tid)*2+1]+s_ep[(3*64+tid)*2+1];
      eS[bm+tid]=se; eD[bm+tid]=sd;
    }
  }
  // ---- z bf16 write (pair-pack via shfl) ----
#pragma unroll
  for (int m=0;m<4;m++)
#pragma unroll
    for (int n=0;n<4;n++)
#pragma unroll
      for (int j=0;j<4;j++){
        float v0 = acc[m][n][j];
        float v1 = __shfl_down(v0,1,64);
        if (!(lane&1)){
          unsigned pk = (unsigned)f2bf(v0) | ((unsigned)f2bf(v1)<<16);
          int row = bm + m*16 + kg*4 + j, cc = w*64 + n*16 + r15;
          *(unsigned*)(zb + (size_t)row*256 + cc) = pk;
        }
      }
}

// ---------------- layer-1: wave-per-dst softmax + aggregate, h1 = elu(m) (bf16 out) ----------
__global__ __launch_bounds__(256) void agg1_k(const unsigned short* __restrict__ zb,
    const float* __restrict__ es, const float* __restrict__ ed,
    const int* __restrict__ row_off, const int* __restrict__ col,
    unsigned short* __restrict__ h1b, int n){
  __shared__ int   s_src[4][MAXDEG];
  __shared__ float s_al [4][MAXDEG][4];
  int w = threadIdx.x>>6, lane = threadIdx.x&63;
  int nd = blockIdx.x*4 + w;
  if (nd>=n) return;
  int beg=row_off[nd], deg=row_off[nd+1]-beg;
  float4 edv = *(const float4*)(ed + (size_t)nd*4);
  float m0=-1e30f,m1=-1e30f,m2=-1e30f,m3=-1e30f;
  for (int j=lane;j<deg;j+=64){
    int s=col[beg+j];
    float4 ev = *((const float4*)es + s);
    ev.x=leaky1(ev.x+edv.x); ev.y=leaky1(ev.y+edv.y);
    ev.z=leaky1(ev.z+edv.z); ev.w=leaky1(ev.w+edv.w);
    if (j<MAXDEG){
      s_src[w][j]=s;
      s_al[w][j][0]=ev.x; s_al[w][j][1]=ev.y; s_al[w][j][2]=ev.z; s_al[w][j][3]=ev.w;
    }
    m0=fmaxf(m0,ev.x); m1=fmaxf(m1,ev.y); m2=fmaxf(m2,ev.z); m3=fmaxf(m3,ev.w);
  }
  m0=wmax_all(m0); m1=wmax_all(m1); m2=wmax_all(m2); m3=wmax_all(m3);
  float t0=0.f,t1=0.f,t2=0.f,t3=0.f;
  for (int j=lane;j<deg;j+=64){
    float e0,e1,e2,e3;
    if (j<MAXDEG){ e0=s_al[w][j][0]; e1=s_al[w][j][1]; e2=s_al[w][j][2]; e3=s_al[w][j][3]; }
    else {
      int s=col[beg+j];
      float4 ev = *((const float4*)es + s);
      e0=leaky1(ev.x+edv.x); e1=leaky1(ev.y+edv.y); e2=leaky1(ev.z+edv.z); e3=leaky1(ev.w+edv.w);
    }
    e0=__expf(e0-m0); e1=__expf(e1-m1); e2=__expf(e2-m2); e3=__expf(e3-m3);
    if (j<MAXDEG){ s_al[w][j][0]=e0; s_al[w][j][1]=e1; s_al[w][j][2]=e2; s_al[w][j][3]=e3; }
    t0+=e0; t1+=e1; t2+=e2; t3+=e3;
  }
  t0=wsum_all(t0); t1=wsum_all(t1); t2=wsum_all(t2); t3=wsum_all(t3);
  int hh = lane>>4;
  float invh = 1.0f/(hh==0? t0 : hh==1? t1 : hh==2? t2 : t3);
  float mh   = (hh==0? m0 : hh==1? m1 : hh==2? m2 : m3);
  const uint2* zp = (const uint2*)zb;
  float a0=0.f,a1a=0.f,a2a=0.f,a3=0.f;
  int dm = deg<MAXDEG? deg:MAXDEG;
  int j=0;
  for (; j+2<=dm; j+=2){
    int sA=s_src[w][j], sB=s_src[w][j+1];
    float alA=s_al[w][j][hh], alB=s_al[w][j+1][hh];
    uint2 vA = zp[(size_t)((unsigned)sA*64u + (unsigned)lane)];
    uint2 vB = zp[(size_t)((unsigned)sB*64u + (unsigned)lane)];
    a0 += alA*bf_lo(vA.x); a1a += alA*bf_hi(vA.x);
    a2a += alA*bf_lo(vA.y); a3 += alA*bf_hi(vA.y);
    a0 += alB*bf_lo(vB.x); a1a += alB*bf_hi(vB.x);
    a2a += alB*bf_lo(vB.y); a3 += alB*bf_hi(vB.y);
  }
  for (; j<dm; j++){
    int s=s_src[w][j];
    float al=s_al[w][j][hh];
    uint2 v = zp[(size_t)((unsigned)s*64u + (unsigned)lane)];
    a0 += al*bf_lo(v.x); a1a += al*bf_hi(v.x);
    a2a += al*bf_lo(v.y); a3 += al*bf_hi(v.y);
  }
  for (; j<deg; j++){
    int s=col[beg+j];
    float4 ev = *((const float4*)es + s);
    float e = (hh==0? ev.x+edv.x : hh==1? ev.y+edv.y : hh==2? ev.z+edv.z : ev.w+edv.w);
    float al = __expf(leaky1(e)-mh);
    uint2 v = zp[(size_t)((unsigned)s*64u + (unsigned)lane)];
    a0 += al*bf_lo(v.x); a1a += al*bf_hi(v.x);
    a2a += al*bf_lo(v.y); a3 += al*bf_hi(v.y);
  }
  a0*=invh; a1a*=invh; a2a*=invh; a3*=invh;
  a0 = a0>0.f? a0 : __expf(a0)-1.0f;
  a1a= a1a>0.f? a1a: __expf(a1a)-1.0f;
  a2a= a2a>0.f? a2a: __expf(a2a)-1.0f;
  a3 = a3>0.f? a3 : __expf(a3)-1.0f;
  unsigned lo = (unsigned)f2bf(a0) | ((unsigned)f2bf(a1a)<<16);
  unsigned hi = (unsigned)f2bf(a2a) | ((unsigned)f2bf(a3)<<16);
  *(uint2*)(h1b + (size_t)nd*256 + lane*4) = make_uint2(lo,hi);
}

// ---------------- layer-2: wave-per-dst, 1 head, writes out (f32) ----------------
__global__ __launch_bounds__(256) void agg2_k(const unsigned short* __restrict__ zb,
    const float* __restrict__ e2s, const float* __restrict__ e2d,
    const int* __restrict__ row_off, const int* __restrict__ col,
    float* __restrict__ out, int n){
  __shared__ int   s_src[4][MAXDEG];
  __shared__ float s_al [4][MAXDEG];
  int w = threadIdx.x>>6, lane = threadIdx.x&63;
  int nd = blockIdx.x*4 + w;
  if (nd>=n) return;
  int beg=row_off[nd], deg=row_off[nd+1]-beg;
  float edv = e2d[nd];
  float m=-1e30f;
  for (int j=lane;j<deg;j+=64){
    int s=col[beg+j];
    float ev = leaky1(e2s[s]+edv);
    if (j<MAXDEG){ s_src[w][j]=s; s_al[w][j]=ev; }
    m=fmaxf(m,ev);
  }
  m=wmax_all(m);
  float ts=0.f;
  for (int j=lane;j<deg;j+=64){
    float e;
    if (j<MAXDEG) e=s_al[w][j];
    else { int s=col[beg+j]; e=leaky1(e2s[s]+edv); }
    e=__expf(e-m);
    if (j<MAXDEG) s_al[w][j]=e;
    ts+=e;
  }
  ts=wsum_all(ts);
  float inv=1.0f/ts;
  const uint2* zp = (const uint2*)zb;
  float a0=0.f,a1a=0.f,a2a=0.f,a3=0.f;
  int dm = deg<MAXDEG? deg:MAXDEG;
  int j=0;
  for (; j+2<=dm; j+=2){
    int sA=s_src[w][j], sB=s_src[w][j+1];
    float alA=s_al[w][j], alB=s_al[w][j+1];
    uint2 vA = zp[(size_t)((unsigned)sA*64u + (unsigned)lane)];
    uint2 vB = zp[(size_t)((unsigned)sB*64u + (unsigned)lane)];
    a0 += alA*bf_lo(vA.x); a1a += alA*bf_hi(vA.x);
    a2a += alA*bf_lo(vA.y); a3 += alA*bf_hi(vA.y);
    a0 += alB*bf_lo(vB.x); a1a += alB*bf_hi(vB.x);
    a2a += alB*bf_lo(vB.y); a3 += alB*bf_hi(vB.y);
  }
  for (; j<dm; j++){
    int s=s_src[w][j];
    float al=s_al[w][j];
    uint2 v = zp[(size_t)((unsigned)s*64u + (unsigned)lane)];
    a0 += al*bf_lo(v.x); a1a += al*bf_hi(v.x);
    a2a += al*bf_lo(v.y); a3 += al*bf_hi(v.y);
  }
  for (; j<deg; j++){
    int s=col[beg+j];
    float al = __expf(leaky1(e2s[s]+edv)-m);
    uint2 v = zp[(size_t)((unsigned)s*64u + (unsigned)lane)];
    a0 += al*bf_lo(v.x); a1a += al*bf_hi(v.x);
    a2a += al*bf_lo(v.y); a3 += al*bf_hi(v.y);
  }
  *((float4*)out + (size_t)nd*64 + lane) = make_float4(a0*inv,a1a*inv,a2a*inv,a3*inv);
}

// ---------------- launch ----------------
extern "C" void kernel_launch(void* const* d_in, const int* in_sizes, int n_in,
                              void* d_out, int out_size, void* d_ws, size_t ws_size,
                              hipStream_t stream){
  const float* h  = (const float*)d_in[0];
  const float* W1 = (const float*)d_in[1];
  const float* a1 = (const float*)d_in[2];
  const float* W2 = (const float*)d_in[3];
  const float* a2 = (const float*)d_in[4];
  const int* src  = (const int*)d_in[5];
  const int* dst  = (const int*)d_in[6];
  float* out = (float*)d_out;
  int N = in_sizes[0]/256;          // 50000
  int E = in_sizes[5];              // 850000
  int Npad = ((N+63)/64)*64;        // 50048

  char* p=(char*)d_ws;
  auto alloc=[&](size_t bytes)->void*{ void* r=(void*)p; p += (bytes+255)&~(size_t)255; return r; };
  unsigned short* Ab  =(unsigned short*)alloc(sizeof(unsigned short)*(size_t)Npad*256);
  unsigned short* zb  =(unsigned short*)alloc(sizeof(unsigned short)*(size_t)Npad*256);
  unsigned short* z2b =(unsigned short*)alloc(sizeof(unsigned short)*(size_t)Npad*256);
  unsigned short* h1b =(unsigned short*)alloc(sizeof(unsigned short)*(size_t)Npad*256);
  unsigned short* Wb  =(unsigned short*)alloc(sizeof(unsigned short)*131072);
  float* es  =(float*)alloc(sizeof(float)*(size_t)Npad*4);
  float* ed  =(float*)alloc(sizeof(float)*(size_t)Npad*4);
  float* e2s =(float*)alloc(sizeof(float)*(size_t)Npad);
  float* e2d =(float*)alloc(sizeof(float)*(size_t)Npad);
  int* cnt    =(int*)alloc(sizeof(int)*(size_t)N);
  int* row_off=(int*)alloc(sizeof(int)*(size_t)(N+1));
  int* cursor =(int*)alloc(sizeof(int)*(size_t)N);
  int* col    =(int*)alloc(sizeof(int)*(size_t)E);
  int* bsum   =(int*)alloc(sizeof(int)*64);
  int* bpre   =(int*)alloc(sizeof(int)*64);

  int nb = (N+1023)/1024;

  zero_cnt_k<<<(N+255)/256,256,0,stream>>>(cnt,N);
  hist_k<<<(E+255)/256,256,0,stream>>>(dst,cnt,E);
  scan_partial_k<<<nb,256,0,stream>>>(cnt,bsum,N);
  scan_bsums_k<<<1,64,0,stream>>>(bsum,bpre,nb,row_off,N,E);
  scan_final_k<<<nb,256,0,stream>>>(cnt,bpre,row_off,cursor,N);
  scatter_k<<<(E+255)/256,256,0,stream>>>(src,dst,cursor,col,E);

  conv_h_k<<<(Npad*32+255)/256,256,0,stream>>>(h,Ab,N*256,Npad*256);
  conv_w_k<<<64,256,0,stream>>>(W1,W2,Wb);

  int gblocks = Npad/64;
  gemm_mfma<1><<<gblocks,256,0,stream>>>(Ab, Wb, a1, zb, es, ed);
  agg1_k<<<(N+3)/4,256,0,stream>>>(zb,es,ed,row_off,col,h1b,N);
  gemm_mfma<2><<<gblocks,256,0,stream>>>(h1b, Wb+65536, a2, z2b, e2s, e2d);
  agg2_k<<<(N+3)/4,256,0,stream>>>(z2b,e2s,e2d,row_off,col,out,N);
}

// Round 6
// 287.147 us; speedup vs baseline: 2.4145x; 1.0413x over previous
//
#include <hip/hip_runtime.h>
#include <hip/hip_bf16.h>
#include <math.h>

#define NEG 0.01f
#define MAXDEG 128

typedef __attribute__((ext_vector_type(4))) unsigned u32x4;
typedef __attribute__((ext_vector_type(4))) float f32x4;

// ---------------- helpers ----------------
__device__ __forceinline__ float wmax_all(float v){
#pragma unroll
  for (int o=32;o>0;o>>=1) v = fmaxf(v, __shfl_xor(v,o,64));
  return v;
}
__device__ __forceinline__ float wsum_all(float v){
#pragma unroll
  for (int o=32;o>0;o>>=1) v += __shfl_xor(v,o,64);
  return v;
}
__device__ __forceinline__ int wred_sum_i(int v){
#pragma unroll
  for (int o=32;o>0;o>>=1) v += __shfl_down(v,o,64);
  return v;
}
__device__ __forceinline__ float bf_lo(unsigned u){ union{unsigned i;float f;} c; c.i=u<<16; return c.f; }
__device__ __forceinline__ float bf_hi(unsigned u){ union{unsigned i;float f;} c; c.i=u&0xffff0000u; return c.f; }
__device__ __forceinline__ unsigned short f2bf(float f){
  union{float f; unsigned i;} c; c.f=f;
  unsigned r = c.i + 0x7fffu + ((c.i>>16)&1u);
  return (unsigned short)(r>>16);
}
__device__ __forceinline__ unsigned cvtpk(float lo, float hi){   // [lo | hi<<16] bf16 RNE
  unsigned r;
  asm("v_cvt_pk_bf16_f32 %0, %1, %2" : "=v"(r) : "v"(lo), "v"(hi));
  return r;
}
__device__ __forceinline__ float leaky1(float x){ return x>0.f? x : NEG*x; }

__device__ __forceinline__ void mfma16(f32x4& d, u32x4 a, u32x4 b){
  asm volatile("v_mfma_f32_16x16x32_bf16 %0, %1, %2, %0" : "+v"(d) : "v"(a), "v"(b));
}

// ---------------- CSR build ----------------
__global__ void zero_cnt_k(int* __restrict__ cnt, int n){
  int i = blockIdx.x*blockDim.x + threadIdx.x;
  if (i<n) cnt[i]=0;
}

__global__ void hist_k(const int* __restrict__ dst, int* __restrict__ cnt, int E){
  int i = blockIdx.x*blockDim.x+threadIdx.x;
  if (i<E) atomicAdd(&cnt[dst[i]], 1);
}

__global__ void scan_partial_k(const int* __restrict__ cnt, int* __restrict__ bsum, int n){
  int b = blockIdx.x, t = threadIdx.x;
  int base = b*1024 + t*4;
  int s=0;
#pragma unroll
  for (int i=0;i<4;i++){ int idx=base+i; if(idx<n) s+=cnt[idx]; }
  int ws = wred_sum_i(s);
  __shared__ int sw[4];
  int wave=t>>6, lane=t&63;
  if (lane==0) sw[wave]=ws;
  __syncthreads();
  if (t==0) bsum[b] = sw[0]+sw[1]+sw[2]+sw[3];
}

__global__ void scan_bsums_k(const int* __restrict__ bsum, int* __restrict__ bpre,
                             int nb, int* __restrict__ row_off, int n, int E){
  if (threadIdx.x==0 && blockIdx.x==0){
    int c=0;
    for (int i=0;i<nb;i++){ bpre[i]=c; c+=bsum[i]; }
    row_off[n]=E;
  }
}

__global__ void scan_final_k(const int* __restrict__ cnt, const int* __restrict__ bpre,
                             int* __restrict__ row_off, int* __restrict__ cursor, int n){
  int b=blockIdx.x, t=threadIdx.x;
  int lane=t&63, wave=t>>6;
  int base=b*1024 + t*4;
  int v[4]; int ts=0;
#pragma unroll
  for (int i=0;i<4;i++){ int idx=base+i; v[i]=(idx<n)?cnt[idx]:0; ts+=v[i]; }
  int x=ts;
#pragma unroll
  for (int o=1;o<64;o<<=1){ int y=__shfl_up(x,o,64); if (lane>=o) x+=y; }
  __shared__ int sw[4];
  if (lane==63) sw[wave]=x;
  __syncthreads();
  int wpre=0;
  for (int w=0;w<wave;w++) wpre+=sw[w];
  int run = bpre[b] + wpre + (x - ts);
#pragma unroll
  for (int i=0;i<4;i++){ int idx=base+i; if(idx<n){ row_off[idx]=run; cursor[idx]=run; } run+=v[i]; }
}

__global__ void scatter_k(const int* __restrict__ src, const int* __restrict__ dst,
                          int* __restrict__ cursor, int* __restrict__ col, int E){
  int i=blockIdx.x*blockDim.x+threadIdx.x;
  if (i<E){ int slot=atomicAdd(&cursor[dst[i]],1); col[slot]=src[i]; }
}

// ---------------- weight convert ----------------
__global__ void conv_w_k(const float* __restrict__ W1, const float* __restrict__ W2,
                         unsigned short* __restrict__ Wb){
  int i = blockIdx.x*blockDim.x + threadIdx.x;   // 16384 threads, 8 elems each
  int base = i*8;
  const float* src = (base<65536)? (W1+base) : (W2+(base-65536));
  float4 x=*(const float4*)src, y=*(const float4*)(src+4);
  uint4 o;
  o.x=cvtpk(x.x,x.y); o.y=cvtpk(x.z,x.w);
  o.z=cvtpk(y.x,y.y); o.w=cvtpk(y.z,y.w);
  *(uint4*)(Wb+base)=o;
}

// ---------------- MFMA GEMM: C(Npad x 256) = A(Npad x 256) @ W(256 x 256,bf16)^T ------------
// BM=64, BN=256 (one block spans all cols; A read once), BK=64, 4 waves (wave = 64-col quadrant)
// L==1: A is f32 (h) -> cvt in stage (conv_h fused).  L==2: A is bf16 (h1b).
// Fused epilogue: z bf16 + es/ed (L==1: per-wave head; L==2: cross-wave LDS reduce)
template<int L>
__global__ __launch_bounds__(256) void gemm_mfma(const void* __restrict__ Aptr,
    const unsigned short* __restrict__ Wb, const float* __restrict__ av,
    unsigned short* __restrict__ zb, float* __restrict__ eS, float* __restrict__ eD, int n){
  __shared__ char lds[40960];            // A: [64][64]bf16 8KB | B: [256][64]bf16 32KB @8192
  const int tid=threadIdx.x, lane=tid&63, w=tid>>6;
  const int r15=lane&15, kg=lane>>4;
  const int bm = blockIdx.x*64;
  const float* Af = (const float*)Aptr;                   // L==1
  const char*  Ag = (const char*)Aptr + (size_t)bm*512;   // L==2, row stride 512B
  const char*  Bg = (const char*)Wb;
  auto stage=[&](int kt){
#pragma unroll
    for (int i=0;i<2;i++){
      int o=tid*16+i*4096, row=o>>7, cb=o&127;
      uint4 v;
      if (L==1){
        int gr = bm+row; if (gr>=n) gr=n-1;
        const float* s = Af + (size_t)gr*256 + kt*64 + (cb>>1);
        float4 x=*(const float4*)s, y=*(const float4*)(s+4);
        v.x=cvtpk(x.x,x.y); v.y=cvtpk(x.z,x.w);
        v.z=cvtpk(y.x,y.y); v.w=cvtpk(y.z,y.w);
      } else {
        v = *(const uint4*)(Ag + (size_t)row*512 + kt*128 + cb);
      }
      *(uint4*)(lds + (o ^ ((row&7)<<4))) = v;
    }
#pragma unroll
    for (int i=0;i<8;i++){
      int o=tid*16+i*4096, row=o>>7, cb=o&127;
      uint4 v = *(const uint4*)(Bg + (size_t)row*512 + kt*128 + cb);
      *(uint4*)(lds + 8192 + (o ^ ((row&7)<<4))) = v;
    }
  };
  f32x4 acc[4][4];
  f32x4 z4 = {0.f,0.f,0.f,0.f};
#pragma unroll
  for (int m=0;m<4;m++)
#pragma unroll
    for (int n2=0;n2<4;n2++) acc[m][n2]=z4;

  for (int kt=0;kt<4;kt++){
    if (kt) __syncthreads();           // prior tile's reads done before overwrite
    stage(kt);
    __syncthreads();
#pragma unroll
    for (int kk=0;kk<2;kk++){
      u32x4 af[4], bf[4];
#pragma unroll
      for (int m=0;m<4;m++){
        int row = m*16 + r15;
        int off = row*128 + kk*64 + kg*16;
        af[m] = *(const u32x4*)(lds + (off ^ ((row&7)<<4)));
      }
#pragma unroll
      for (int n2=0;n2<4;n2++){
        int c = w*64 + n2*16 + r15;
        int off = c*128 + kk*64 + kg*16;
        bf[n2] = *(const u32x4*)(lds + 8192 + (off ^ ((c&7)<<4)));
      }
#pragma unroll
      for (int m=0;m<4;m++)
#pragma unroll
        for (int n2=0;n2<4;n2++) mfma16(acc[m][n2], af[m], bf[n2]);
    }
  }
  asm volatile("s_nop 7\n\ts_nop 7");   // MFMA->VALU read spacing
  // ---- es/ed epilogue ----
  float avs[4], avd[4];
#pragma unroll
  for (int n2=0;n2<4;n2++){
    int c = n2*16 + r15;
    if (L==1){ avs[n2]=av[w*128 + c];      avd[n2]=av[w*128 + 64 + c]; }
    else     { avs[n2]=av[w*64 + c];       avd[n2]=av[256 + w*64 + c]; }
  }
  __syncthreads();                       // all ds_reads of tile data complete -> safe LDS reuse
  float* s_ep = (float*)lds;             // [4][64][2]
#pragma unroll
  for (int m=0;m<4;m++)
#pragma unroll
    for (int j=0;j<4;j++){
      float pe=0.f, pd=0.f;
#pragma unroll
      for (int n2=0;n2<4;n2++){ pe += acc[m][n2][j]*avs[n2]; pd += acc[m][n2][j]*avd[n2]; }
#pragma unroll
      for (int o=1;o<16;o<<=1){ pe += __shfl_xor(pe,o,64); pd += __shfl_xor(pd,o,64); }
      if (r15==0){
        int lrow = m*16 + kg*4 + j;
        if (L==1){ eS[(size_t)(bm+lrow)*4 + w]=pe; eD[(size_t)(bm+lrow)*4 + w]=pd; }
        else     { s_ep[(w*64+lrow)*2]=pe; s_ep[(w*64+lrow)*2+1]=pd; }
      }
    }
  if (L==2){
    __syncthreads();
    if (tid<64){
      float se = s_ep[(0*64+tid)*2]+s_ep[(1*64+tid)*2]+s_ep[(2*64+tid)*2]+s_ep[(3*64+tid)*2];
      float sd = s_ep[(0*64+tid)*2+1]+s_ep[(1*64+tid)*2+1]+s_ep[(2*64+tid)*2+1]+s_ep[(3*64+tid)*2+1];
      eS[bm+tid]=se; eD[bm+tid]=sd;
    }
  }
  // ---- z bf16 write (pair-pack via shfl) ----
#pragma unroll
  for (int m=0;m<4;m++)
#pragma unroll
    for (int n2=0;n2<4;n2++)
#pragma unroll
      for (int j=0;j<4;j++){
        float v0 = acc[m][n2][j];
        float v1 = __shfl_down(v0,1,64);
        if (!(lane&1)){
          unsigned pk = cvtpk(v0,v1);
          int row = bm + m*16 + kg*4 + j, cc = w*64 + n2*16 + r15;
          *(unsigned*)(zb + (size_t)row*256 + cc) = pk;
        }
      }
}

// ---------------- layer-1: wave-per-dst softmax + aggregate, h1 = elu(m) (bf16 out) ----------
__global__ __launch_bounds__(256) void agg1_k(const unsigned short* __restrict__ zb,
    const float* __restrict__ es, const float* __restrict__ ed,
    const int* __restrict__ row_off, const int* __restrict__ col,
    unsigned short* __restrict__ h1b, int n){
  __shared__ int   s_src[4][MAXDEG];
  __shared__ float s_al [4][MAXDEG][4];
  int w = threadIdx.x>>6, lane = threadIdx.x&63;
  int nd = blockIdx.x*4 + w;
  if (nd>=n) return;
  int beg=row_off[nd], deg=row_off[nd+1]-beg;
  float4 edv = *(const float4*)(ed + (size_t)nd*4);
  float m0=-1e30f,m1=-1e30f,m2=-1e30f,m3=-1e30f;
  for (int j=lane;j<deg;j+=64){
    int s=col[beg+j];
    float4 ev = *((const float4*)es + s);
    ev.x=leaky1(ev.x+edv.x); ev.y=leaky1(ev.y+edv.y);
    ev.z=leaky1(ev.z+edv.z); ev.w=leaky1(ev.w+edv.w);
    if (j<MAXDEG){
      s_src[w][j]=s;
      s_al[w][j][0]=ev.x; s_al[w][j][1]=ev.y; s_al[w][j][2]=ev.z; s_al[w][j][3]=ev.w;
    }
    m0=fmaxf(m0,ev.x); m1=fmaxf(m1,ev.y); m2=fmaxf(m2,ev.z); m3=fmaxf(m3,ev.w);
  }
  m0=wmax_all(m0); m1=wmax_all(m1); m2=wmax_all(m2); m3=wmax_all(m3);
  float t0=0.f,t1=0.f,t2=0.f,t3=0.f;
  for (int j=lane;j<deg;j+=64){
    float e0,e1,e2,e3;
    if (j<MAXDEG){ e0=s_al[w][j][0]; e1=s_al[w][j][1]; e2=s_al[w][j][2]; e3=s_al[w][j][3]; }
    else {
      int s=col[beg+j];
      float4 ev = *((const float4*)es + s);
      e0=leaky1(ev.x+edv.x); e1=leaky1(ev.y+edv.y); e2=leaky1(ev.z+edv.z); e3=leaky1(ev.w+edv.w);
    }
    e0=__expf(e0-m0); e1=__expf(e1-m1); e2=__expf(e2-m2); e3=__expf(e3-m3);
    if (j<MAXDEG){ s_al[w][j][0]=e0; s_al[w][j][1]=e1; s_al[w][j][2]=e2; s_al[w][j][3]=e3; }
    t0+=e0; t1+=e1; t2+=e2; t3+=e3;
  }
  t0=wsum_all(t0); t1=wsum_all(t1); t2=wsum_all(t2); t3=wsum_all(t3);
  int hh = lane>>4;
  float invh = 1.0f/(hh==0? t0 : hh==1? t1 : hh==2? t2 : t3);
  float mh   = (hh==0? m0 : hh==1? m1 : hh==2? m2 : m3);
  const uint2* zp = (const uint2*)zb;
  float a0=0.f,a1a=0.f,a2a=0.f,a3=0.f;
  int dm = deg<MAXDEG? deg:MAXDEG;
  int j=0;
  for (; j+4<=dm; j+=4){                 // 4 gathers in flight
    int s0=s_src[w][j],   s1=s_src[w][j+1], s2=s_src[w][j+2], s3=s_src[w][j+3];
    float b0=s_al[w][j][hh],   b1=s_al[w][j+1][hh];
    float b2=s_al[w][j+2][hh], b3=s_al[w][j+3][hh];
    uint2 v0 = zp[(size_t)((unsigned)s0*64u + (unsigned)lane)];
    uint2 v1 = zp[(size_t)((unsigned)s1*64u + (unsigned)lane)];
    uint2 v2 = zp[(size_t)((unsigned)s2*64u + (unsigned)lane)];
    uint2 v3 = zp[(size_t)((unsigned)s3*64u + (unsigned)lane)];
    a0 += b0*bf_lo(v0.x); a1a += b0*bf_hi(v0.x); a2a += b0*bf_lo(v0.y); a3 += b0*bf_hi(v0.y);
    a0 += b1*bf_lo(v1.x); a1a += b1*bf_hi(v1.x); a2a += b1*bf_lo(v1.y); a3 += b1*bf_hi(v1.y);
    a0 += b2*bf_lo(v2.x); a1a += b2*bf_hi(v2.x); a2a += b2*bf_lo(v2.y); a3 += b2*bf_hi(v2.y);
    a0 += b3*bf_lo(v3.x); a1a += b3*bf_hi(v3.x); a2a += b3*bf_lo(v3.y); a3 += b3*bf_hi(v3.y);
  }
  for (; j<dm; j++){
    int s=s_src[w][j];
    float al=s_al[w][j][hh];
    uint2 v = zp[(size_t)((unsigned)s*64u + (unsigned)lane)];
    a0 += al*bf_lo(v.x); a1a += al*bf_hi(v.x);
    a2a += al*bf_lo(v.y); a3 += al*bf_hi(v.y);
  }
  for (; j<deg; j++){       // never-taken fallback
    int s=col[beg+j];
    float4 ev = *((const float4*)es + s);
    float e = (hh==0? ev.x+edv.x : hh==1? ev.y+edv.y : hh==2? ev.z+edv.z : ev.w+edv.w);
    float al = __expf(leaky1(e)-mh);
    uint2 v = zp[(size_t)((unsigned)s*64u + (unsigned)lane)];
    a0 += al*bf_lo(v.x); a1a += al*bf_hi(v.x);
    a2a += al*bf_lo(v.y); a3 += al*bf_hi(v.y);
  }
  a0*=invh; a1a*=invh; a2a*=invh; a3*=invh;
  a0 = a0>0.f? a0 : __expf(a0)-1.0f;
  a1a= a1a>0.f? a1a: __expf(a1a)-1.0f;
  a2a= a2a>0.f? a2a: __expf(a2a)-1.0f;
  a3 = a3>0.f? a3 : __expf(a3)-1.0f;
  *(uint2*)(h1b + (size_t)nd*256 + lane*4) = make_uint2(cvtpk(a0,a1a), cvtpk(a2a,a3));
}

// ---------------- layer-2: wave-per-dst, 1 head, writes out (f32) ----------------
__global__ __launch_bounds__(256) void agg2_k(const unsigned short* __restrict__ zb,
    const float* __restrict__ e2s, const float* __restrict__ e2d,
    const int* __restrict__ row_off, const int* __restrict__ col,
    float* __restrict__ out, int n){
  __shared__ int   s_src[4][MAXDEG];
  __shared__ float s_al [4][MAXDEG];
  int w = threadIdx.x>>6, lane = threadIdx.x&63;
  int nd = blockIdx.x*4 + w;
  if (nd>=n) return;
  int beg=row_off[nd], deg=row_off[nd+1]-beg;
  float edv = e2d[nd];
  float m=-1e30f;
  for (int j=lane;j<deg;j+=64){
    int s=col[beg+j];
    float ev = leaky1(e2s[s]+edv);
    if (j<MAXDEG){ s_src[w][j]=s; s_al[w][j]=ev; }
    m=fmaxf(m,ev);
  }
  m=wmax_all(m);
  float ts=0.f;
  for (int j=lane;j<deg;j+=64){
    float e;
    if (j<MAXDEG) e=s_al[w][j];
    else { int s=col[beg+j]; e=leaky1(e2s[s]+edv); }
    e=__expf(e-m);
    if (j<MAXDEG) s_al[w][j]=e;
    ts+=e;
  }
  ts=wsum_all(ts);
  float inv=1.0f/ts;
  const uint2* zp = (const uint2*)zb;
  float a0=0.f,a1a=0.f,a2a=0.f,a3=0.f;
  int dm = deg<MAXDEG? deg:MAXDEG;
  int j=0;
  for (; j+4<=dm; j+=4){                 // 4 gathers in flight
    int s0=s_src[w][j],   s1=s_src[w][j+1], s2=s_src[w][j+2], s3=s_src[w][j+3];
    float b0=s_al[w][j],   b1=s_al[w][j+1], b2=s_al[w][j+2], b3=s_al[w][j+3];
    uint2 v0 = zp[(size_t)((unsigned)s0*64u + (unsigned)lane)];
    uint2 v1 = zp[(size_t)((unsigned)s1*64u + (unsigned)lane)];
    uint2 v2 = zp[(size_t)((unsigned)s2*64u + (unsigned)lane)];
    uint2 v3 = zp[(size_t)((unsigned)s3*64u + (unsigned)lane)];
    a0 += b0*bf_lo(v0.x); a1a += b0*bf_hi(v0.x); a2a += b0*bf_lo(v0.y); a3 += b0*bf_hi(v0.y);
    a0 += b1*bf_lo(v1.x); a1a += b1*bf_hi(v1.x); a2a += b1*bf_lo(v1.y); a3 += b1*bf_hi(v1.y);
    a0 += b2*bf_lo(v2.x); a1a += b2*bf_hi(v2.x); a2a += b2*bf_lo(v2.y); a3 += b2*bf_hi(v2.y);
    a0 += b3*bf_lo(v3.x); a1a += b3*bf_hi(v3.x); a2a += b3*bf_lo(v3.y); a3 += b3*bf_hi(v3.y);
  }
  for (; j<dm; j++){
    int s=s_src[w][j];
    float al=s_al[w][j];
    uint2 v = zp[(size_t)((unsigned)s*64u + (unsigned)lane)];
    a0 += al*bf_lo(v.x); a1a += al*bf_hi(v.x);
    a2a += al*bf_lo(v.y); a3 += al*bf_hi(v.y);
  }
  for (; j<deg; j++){
    int s=col[beg+j];
    float al = __expf(leaky1(e2s[s]+edv)-m);
    uint2 v = zp[(size_t)((unsigned)s*64u + (unsigned)lane)];
    a0 += al*bf_lo(v.x); a1a += al*bf_hi(v.x);
    a2a += al*bf_lo(v.y); a3 += al*bf_hi(v.y);
  }
  *((float4*)out + (size_t)nd*64 + lane) = make_float4(a0*inv,a1a*inv,a2a*inv,a3*inv);
}

// ---------------- launch ----------------
extern "C" void kernel_launch(void* const* d_in, const int* in_sizes, int n_in,
                              void* d_out, int out_size, void* d_ws, size_t ws_size,
                              hipStream_t stream){
  const float* h  = (const float*)d_in[0];
  const float* W1 = (const float*)d_in[1];
  const float* a1 = (const float*)d_in[2];
  const float* W2 = (const float*)d_in[3];
  const float* a2 = (const float*)d_in[4];
  const int* src  = (const int*)d_in[5];
  const int* dst  = (const int*)d_in[6];
  float* out = (float*)d_out;
  int N = in_sizes[0]/256;          // 50000
  int E = in_sizes[5];              // 850000
  int Npad = ((N+63)/64)*64;        // 50048

  char* p=(char*)d_ws;
  auto alloc=[&](size_t bytes)->void*{ void* r=(void*)p; p += (bytes+255)&~(size_t)255; return r; };
  unsigned short* zb  =(unsigned short*)alloc(sizeof(unsigned short)*(size_t)Npad*256);
  unsigned short* z2b =(unsigned short*)alloc(sizeof(unsigned short)*(size_t)Npad*256);
  unsigned short* h1b =(unsigned short*)alloc(sizeof(unsigned short)*(size_t)Npad*256);
  unsigned short* Wb  =(unsigned short*)alloc(sizeof(unsigned short)*131072);
  float* es  =(float*)alloc(sizeof(float)*(size_t)Npad*4);
  float* ed  =(float*)alloc(sizeof(float)*(size_t)Npad*4);
  float* e2s =(float*)alloc(sizeof(float)*(size_t)Npad);
  float* e2d =(float*)alloc(sizeof(float)*(size_t)Npad);
  int* cnt    =(int*)alloc(sizeof(int)*(size_t)N);
  int* row_off=(int*)alloc(sizeof(int)*(size_t)(N+1));
  int* cursor =(int*)alloc(sizeof(int)*(size_t)N);
  int* col    =(int*)alloc(sizeof(int)*(size_t)E);
  int* bsum   =(int*)alloc(sizeof(int)*64);
  int* bpre   =(int*)alloc(sizeof(int)*64);

  int nb = (N+1023)/1024;

  zero_cnt_k<<<(N+255)/256,256,0,stream>>>(cnt,N);
  hist_k<<<(E+255)/256,256,0,stream>>>(dst,cnt,E);
  scan_partial_k<<<nb,256,0,stream>>>(cnt,bsum,N);
  scan_bsums_k<<<1,64,0,stream>>>(bsum,bpre,nb,row_off,N,E);
  scan_final_k<<<nb,256,0,stream>>>(cnt,bpre,row_off,cursor,N);
  scatter_k<<<(E+255)/256,256,0,stream>>>(src,dst,cursor,col,E);

  conv_w_k<<<64,256,0,stream>>>(W1,W2,Wb);

  int gblocks = Npad/64;
  gemm_mfma<1><<<gblocks,256,0,stream>>>((const void*)h,   Wb,       a1, zb,  es,  ed,  N);
  agg1_k<<<(N+3)/4,256,0,stream>>>(zb,es,ed,row_off,col,h1b,N);
  gemm_mfma<2><<<gblocks,256,0,stream>>>((const void*)h1b, Wb+65536, a2, z2b, e2s, e2d, N);
  agg2_k<<<(N+3)/4,256,0,stream>>>(z2b,e2s,e2d,row_off,col,out,N);
}